// Round 6
// baseline (238.343 us; speedup 1.0000x reference)
//
#include <hip/hip_runtime.h>
#include <hip/hip_bf16.h>

#define H   768
#define H4  3072
#define S   256
#define BB  2
#define M   (BB * S)          // 512 rows of (b,t)
#define LRC 0.01f
#define C   64                // chunk size
#define NC  (S / C)           // 4 chunks

typedef __attribute__((ext_vector_type(8))) short bf16x8;
typedef __attribute__((ext_vector_type(4))) float f32x4;

__device__ inline short bfbits(float f) {
    __hip_bfloat16 h = __float2bfloat16(f);
    return *reinterpret_cast<short*>(&h);
}

// ---------------- K_stage: all input staging in ONE kernel ----------------
__global__ __launch_bounds__(256) void k_stage(
    const float* __restrict__ x,  const float* __restrict__ W0,
    const float* __restrict__ gw, const float* __restrict__ uw,
    const float* __restrict__ dw,
    short* __restrict__ Xhi, short* __restrict__ Xlo,
    short* __restrict__ Whi, short* __restrict__ Wlo,
    short* __restrict__ gw2, short* __restrict__ uw2, short* __restrict__ dw2)
{
    const long gid = (long)blockIdx.x * 256 + threadIdx.x;
    const float* src; short* hp; short* lp = nullptr; long base;
    if (gid < 98304)        { src = x;  hp = Xhi; lp = Xlo; base = 0; }
    else if (gid < 245760)  { src = W0; hp = Whi; lp = Wlo; base = 98304; }
    else if (gid < 835584)  { src = gw; hp = gw2; base = 245760; }
    else if (gid < 1425408) { src = uw; hp = uw2; base = 835584; }
    else                    { src = dw; hp = dw2; base = 1425408; }
    const long i = (gid - base) * 4;
    const float4 v = *(const float4*)(src + i);
    const float vf[4] = {v.x, v.y, v.z, v.w};
    short h4[4], l4[4];
#pragma unroll
    for (int j = 0; j < 4; ++j) {
        h4[j] = bfbits(vf[j]);
        __hip_bfloat16 hb = *reinterpret_cast<__hip_bfloat16*>(&h4[j]);
        l4[j] = bfbits(vf[j] - __bfloat162float(hb));
    }
    *(uint2*)(hp + i) = *(uint2*)h4;
    if (lp) *(uint2*)(lp + i) = *(uint2*)l4;
}

// ---------------- K_gram_base: merged Gram + Base0 GEMMs ------------------
__global__ __launch_bounds__(256) void k_gram_base(
    const short* __restrict__ Xhi, const short* __restrict__ Xlo,
    const short* __restrict__ Whi, const short* __restrict__ Wlo,
    const float* __restrict__ b0,
    float* __restrict__ g, float* __restrict__ base0)
{
    const int wid = threadIdx.x >> 6, lane = threadIdx.x & 63;
    const int r16 = lane & 15, quad = lane >> 4;
    const int id = blockIdx.x;

    f32x4 acc[4];
#pragma unroll
    for (int i = 0; i < 4; ++i) acc[i] = (f32x4){0, 0, 0, 0};

    if (id < 32) {  // ---- gram ----
        const int bx = id & 3, by = (id >> 2) & 3, b = id >> 4;
        const int m0 = by * 64, n0 = bx * 64 + wid * 16;
        const short* XH = Xhi + b * S * H;
        const short* XL = Xlo + b * S * H;
        for (int k0 = 0; k0 < H; k0 += 32) {
            const int k = k0 + quad * 8;
            const bf16x8 bh = *(const bf16x8*)(XH + (n0 + r16) * H + k);
            const bf16x8 bl = *(const bf16x8*)(XL + (n0 + r16) * H + k);
#pragma unroll
            for (int i = 0; i < 4; ++i) {
                const bf16x8 ah = *(const bf16x8*)(XH + (m0 + i * 16 + r16) * H + k);
                const bf16x8 al = *(const bf16x8*)(XL + (m0 + i * 16 + r16) * H + k);
                acc[i] = __builtin_amdgcn_mfma_f32_16x16x32_bf16(ah, bh, acc[i], 0, 0, 0);
                acc[i] = __builtin_amdgcn_mfma_f32_16x16x32_bf16(ah, bl, acc[i], 0, 0, 0);
                acc[i] = __builtin_amdgcn_mfma_f32_16x16x32_bf16(al, bh, acc[i], 0, 0, 0);
            }
        }
        const int col = n0 + r16;
#pragma unroll
        for (int i = 0; i < 4; ++i)
#pragma unroll
            for (int r = 0; r < 4; ++r) {
                const int row = m0 + i * 16 + quad * 4 + r;
                g[(b * S + row) * S + col] = acc[i][r] + 1.f;
            }
    } else {        // ---- base ----
        const int id2 = id - 32;
        const int m0 = (id2 / 12) * 64, n0 = (id2 % 12) * 64 + wid * 16;
        for (int k0 = 0; k0 < H; k0 += 32) {
            const int k = k0 + quad * 8;
            const bf16x8 bh = *(const bf16x8*)(Whi + (n0 + r16) * H + k);
            const bf16x8 bl = *(const bf16x8*)(Wlo + (n0 + r16) * H + k);
#pragma unroll
            for (int i = 0; i < 4; ++i) {
                const bf16x8 ah = *(const bf16x8*)(Xhi + (m0 + i * 16 + r16) * H + k);
                const bf16x8 al = *(const bf16x8*)(Xlo + (m0 + i * 16 + r16) * H + k);
                acc[i] = __builtin_amdgcn_mfma_f32_16x16x32_bf16(ah, bh, acc[i], 0, 0, 0);
                acc[i] = __builtin_amdgcn_mfma_f32_16x16x32_bf16(ah, bl, acc[i], 0, 0, 0);
                acc[i] = __builtin_amdgcn_mfma_f32_16x16x32_bf16(al, bh, acc[i], 0, 0, 0);
            }
        }
        const int col = n0 + r16;
        const float bv = b0[col];
#pragma unroll
        for (int i = 0; i < 4; ++i)
#pragma unroll
            for (int r = 0; r < 4; ++r) {
                const int row = m0 + i * 16 + quad * 4 + r;
                base0[row * H + col] = acc[i][r] + bv;
            }
    }
}

// ---------------- K_inv: U_c = T_c^{-1} for each (b, chunk) ---------------
// T_c[t][s] = delta(t,s) + LR*G[t0+s][t0+t] (s<t). 8 wgs; wave w solves
// columns [w*16, w*16+16) by forward substitution (only serial part left).
__global__ __launch_bounds__(256) void k_inv(
    const float* __restrict__ g, float* __restrict__ U)
{
    __shared__ float Gi[C * 65];
    const int tid = threadIdx.x;
    const int w = tid >> 6, lane = tid & 63;
    const int b = blockIdx.x >> 2, c = blockIdx.x & 3;
    const int t0 = c * C;

#pragma unroll
    for (int j = 0; j < 16; ++j) {
        const int idx = tid + 256 * j;
        const int row = idx >> 6, col = idx & 63;
        Gi[row * 65 + col] = g[(long)(b * S + t0 + row) * S + t0 + col];
    }
    __syncthreads();

    const int j0 = w * 16;
    float R[16];
#pragma unroll
    for (int i = 0; i < 16; ++i) R[i] = (lane == j0 + i) ? 1.f : 0.f;

    for (int s = 0; s < C - 1; ++s) {
        const float Gv = Gi[s * 65 + lane];
        const float mlt = (lane > s) ? LRC : 0.f;
#pragma unroll
        for (int i = 0; i < 16; ++i) {
            const float dsb = __shfl(R[i], s, 64);
            R[i] -= mlt * Gv * dsb;
        }
    }
    float* Ub = U + (long)(b * NC + c) * C * C;
#pragma unroll
    for (int i = 0; i < 16; ++i)
        Ub[lane * C + j0 + i] = R[i];
}

// ---------------- K_recur4: solve via precomputed U (no serial chains) ---
__global__ __launch_bounds__(256) void k_recur4(
    const float* __restrict__ x,
    const float* __restrict__ base0,
    const float* __restrict__ g,
    const float* __restrict__ U,
    float* __restrict__ pred_f,
    __hip_bfloat16* __restrict__ pred_h)
{
    __shared__ float tB[64 * 17];
    __shared__ float tX[64 * 17];
    __shared__ float Dl[256 * 17];
    __shared__ float Us[64 * 65];
    const int tid = threadIdx.x;
    const int w = tid >> 6, lane = tid & 63;
    const int b = blockIdx.x / 48, hb = blockIdx.x % 48;
    const int h0 = hb * 16;
    const int ho = w * 4;
    const int ct = tid >> 2;
    const int cq = (tid & 3) * 4;

    for (int c = 0; c < NC; ++c) {
        const int t0 = c * C;
        __syncthreads();
        {   // stage tB = Base0 - Xn, tX = Xn, Us = U_c
            const int gm = b * S + t0 + ct;
            const float4 bv = *(const float4*)(base0 + gm * H + h0 + cq);
            float4 xv = {0.f, 0.f, 0.f, 0.f};
            if (t0 + ct + 1 < S)
                xv = *(const float4*)(x + (gm + 1) * H + h0 + cq);
            tB[ct * 17 + cq + 0] = bv.x - xv.x;
            tB[ct * 17 + cq + 1] = bv.y - xv.y;
            tB[ct * 17 + cq + 2] = bv.z - xv.z;
            tB[ct * 17 + cq + 3] = bv.w - xv.w;
            tX[ct * 17 + cq + 0] = xv.x;
            tX[ct * 17 + cq + 1] = xv.y;
            tX[ct * 17 + cq + 2] = xv.z;
            tX[ct * 17 + cq + 3] = xv.w;
            const float* Ub = U + (long)(b * NC + c) * C * C;
#pragma unroll
            for (int j = 0; j < 16; ++j) {
                const int idx = tid + 256 * j;
                const int row = idx >> 6, col = idx & 63;
                Us[row * 65 + col] = Ub[row * C + col];
            }
        }
        __syncthreads();
        float R[4], Xn[4];
#pragma unroll
        for (int h = 0; h < 4; ++h) {
            R[h]  = tB[lane * 17 + ho + h];
            Xn[h] = tX[lane * 17 + ho + h];
        }
        // cross-chunk corrections: R[t] -= LR * G[cs, t0+t] * D[cs]
        const float* gcol = g + (long)(b * S) * S + t0 + lane;
#pragma unroll 4
        for (int cs = 0; cs < t0; ++cs) {
            const float Gv = gcol[(long)cs * S];
            const float* dr = &Dl[cs * 17 + ho];
            R[0] -= LRC * Gv * dr[0];
            R[1] -= LRC * Gv * dr[1];
            R[2] -= LRC * Gv * dr[2];
            R[3] -= LRC * Gv * dr[3];
        }
        // D = U * R'  (broadcast-based, no serial dependency)
        float D[4] = {0.f, 0.f, 0.f, 0.f};
#pragma unroll 8
        for (int s = 0; s < C; ++s) {
            const float Gv = Us[lane * 65 + s];     // U[t=lane][s]
#pragma unroll
            for (int h = 0; h < 4; ++h) {
                const float dsb = __shfl(R[h], s, 64);
                D[h] += Gv * dsb;
            }
        }
#pragma unroll
        for (int h = 0; h < 4; ++h) Dl[(t0 + lane) * 17 + ho + h] = D[h];
        __syncthreads();
#pragma unroll
        for (int h = 0; h < 4; ++h) tB[lane * 17 + ho + h] = D[h] + Xn[h];
        __syncthreads();
        {
            const int gm = b * S + t0 + ct;
            float4 pv;
            pv.x = tB[ct * 17 + cq + 0];
            pv.y = tB[ct * 17 + cq + 1];
            pv.z = tB[ct * 17 + cq + 2];
            pv.w = tB[ct * 17 + cq + 3];
            *(float4*)(pred_f + gm * H + h0 + cq) = pv;
            short p4[4];
            p4[0] = bfbits(pv.x); p4[1] = bfbits(pv.y);
            p4[2] = bfbits(pv.z); p4[3] = bfbits(pv.w);
            *(uint2*)((short*)pred_h + gm * H + h0 + cq) = *(uint2*)p4;
        }
    }
}

// ---------------- K_gateup3: LDS-tiled fused gate+up GEMM ----------------
#define RS 40
__global__ __launch_bounds__(256) void k_gateup3(
    const __hip_bfloat16* __restrict__ predh,
    const short* __restrict__ gwp, const float* __restrict__ gb,
    const short* __restrict__ uwp, const float* __restrict__ ub,
    __hip_bfloat16* __restrict__ hid)
{
    __shared__ int4 smv[1600];           // 25600 B
    short* sm = (short*)smv;
    short* sA = sm;                      // 64  x RS
    short* sG = sm + 64 * RS;            // 128 x RS
    short* sU = sm + (64 + 128) * RS;    // 128 x RS

    const int tid = threadIdx.x;
    const int wid = tid >> 6, lane = tid & 63;
    const int r16 = lane & 15, quad = lane >> 4;
    const int wm = wid & 1, wn = wid >> 1;
    const int n0 = blockIdx.x * 128;
    const int m0 = blockIdx.y * 64;

    const int srow = tid >> 2;
    const int sch  = (tid & 3) * 8;
    const short* A = (const short*)predh;

    f32x4 ag[2][4], au[2][4];
#pragma unroll
    for (int i = 0; i < 2; ++i)
#pragma unroll
        for (int j = 0; j < 4; ++j) { ag[i][j] = (f32x4){0,0,0,0}; au[i][j] = (f32x4){0,0,0,0}; }

    int4 rA, rG0, rG1, rU0, rU1;
    {
        const int k = sch;
        rA  = *(const int4*)(A   + (m0 + srow) * H + k);
        rG0 = *(const int4*)(gwp + (n0 + srow) * H + k);
        rG1 = *(const int4*)(gwp + (n0 + 64 + srow) * H + k);
        rU0 = *(const int4*)(uwp + (n0 + srow) * H + k);
        rU1 = *(const int4*)(uwp + (n0 + 64 + srow) * H + k);
    }
    for (int it = 0; it < 24; ++it) {
        *(int4*)(sA + srow * RS + sch)        = rA;
        *(int4*)(sG + srow * RS + sch)        = rG0;
        *(int4*)(sG + (64 + srow) * RS + sch) = rG1;
        *(int4*)(sU + srow * RS + sch)        = rU0;
        *(int4*)(sU + (64 + srow) * RS + sch) = rU1;
        __syncthreads();
        if (it < 23) {
            const int k = (it + 1) * 32 + sch;
            rA  = *(const int4*)(A   + (m0 + srow) * H + k);
            rG0 = *(const int4*)(gwp + (n0 + srow) * H + k);
            rG1 = *(const int4*)(gwp + (n0 + 64 + srow) * H + k);
            rU0 = *(const int4*)(uwp + (n0 + srow) * H + k);
            rU1 = *(const int4*)(uwp + (n0 + 64 + srow) * H + k);
        }
        bf16x8 aF[2], gF[4], uF[4];
#pragma unroll
        for (int i = 0; i < 2; ++i)
            aF[i] = *(const bf16x8*)(sA + (wm * 32 + i * 16 + r16) * RS + quad * 8);
#pragma unroll
        for (int j = 0; j < 4; ++j) {
            gF[j] = *(const bf16x8*)(sG + (wn * 64 + j * 16 + r16) * RS + quad * 8);
            uF[j] = *(const bf16x8*)(sU + (wn * 64 + j * 16 + r16) * RS + quad * 8);
        }
#pragma unroll
        for (int i = 0; i < 2; ++i)
#pragma unroll
            for (int j = 0; j < 4; ++j) {
                ag[i][j] = __builtin_amdgcn_mfma_f32_16x16x32_bf16(aF[i], gF[j], ag[i][j], 0, 0, 0);
                au[i][j] = __builtin_amdgcn_mfma_f32_16x16x32_bf16(aF[i], uF[j], au[i][j], 0, 0, 0);
            }
        __syncthreads();
    }
#pragma unroll
    for (int j = 0; j < 4; ++j) {
        const int ocol = n0 + wn * 64 + j * 16 + r16;
        const float gbv = gb[ocol], ubv = ub[ocol];
#pragma unroll
        for (int i = 0; i < 2; ++i)
#pragma unroll
            for (int r = 0; r < 4; ++r) {
                const int orow = m0 + wm * 32 + i * 16 + quad * 4 + r;
                const float gg = ag[i][j][r] + gbv;
                const float u  = au[i][j][r] + ubv;
                const float sg = 1.f / (1.f + __expf(-gg));
                hid[orow * H4 + ocol] = __float2bfloat16(sg * u);
            }
    }
}

// ---------------- K_down3: LDS-tiled down GEMM + bias + residual ---------
// 64m x 64n x 32k per wg; wave (wm,wn) = 32m x 32n, 2x2 frags.
__global__ __launch_bounds__(256) void k_down3(
    const __hip_bfloat16* __restrict__ hid,
    const short* __restrict__ dwp, const float* __restrict__ db,
    const float* __restrict__ predf, float* __restrict__ dout)
{
    __shared__ int4 smv[640];            // 10240 B
    short* sm = (short*)smv;
    short* sA = sm;                      // 64 x RS
    short* sB = sm + 64 * RS;            // 64 x RS

    const int tid = threadIdx.x;
    const int wid = tid >> 6, lane = tid & 63;
    const int r16 = lane & 15, quad = lane >> 4;
    const int wm = wid & 1, wn = wid >> 1;
    const int n0 = blockIdx.x * 64;
    const int m0 = blockIdx.y * 64;

    const int srow = tid >> 2;
    const int sch  = (tid & 3) * 8;
    const short* A = (const short*)hid;

    f32x4 ac[2][2];
#pragma unroll
    for (int i = 0; i < 2; ++i)
#pragma unroll
        for (int j = 0; j < 2; ++j) ac[i][j] = (f32x4){0,0,0,0};

    int4 rA, rB;
    rA = *(const int4*)(A   + (m0 + srow) * H4 + sch);
    rB = *(const int4*)(dwp + (n0 + srow) * H4 + sch);
    for (int it = 0; it < 96; ++it) {
        *(int4*)(sA + srow * RS + sch) = rA;
        *(int4*)(sB + srow * RS + sch) = rB;
        __syncthreads();
        if (it < 95) {
            const int k = (it + 1) * 32 + sch;
            rA = *(const int4*)(A   + (m0 + srow) * H4 + k);
            rB = *(const int4*)(dwp + (n0 + srow) * H4 + k);
        }
        bf16x8 aF[2], bF[2];
#pragma unroll
        for (int i = 0; i < 2; ++i) {
            aF[i] = *(const bf16x8*)(sA + (wm * 32 + i * 16 + r16) * RS + quad * 8);
            bF[i] = *(const bf16x8*)(sB + (wn * 32 + i * 16 + r16) * RS + quad * 8);
        }
#pragma unroll
        for (int i = 0; i < 2; ++i)
#pragma unroll
            for (int j = 0; j < 2; ++j)
                ac[i][j] = __builtin_amdgcn_mfma_f32_16x16x32_bf16(aF[i], bF[j], ac[i][j], 0, 0, 0);
        __syncthreads();
    }
#pragma unroll
    for (int j = 0; j < 2; ++j) {
        const int ocol = n0 + wn * 32 + j * 16 + r16;
        const float dbv = db[ocol];
#pragma unroll
        for (int i = 0; i < 2; ++i)
#pragma unroll
            for (int r = 0; r < 4; ++r) {
                const int orow = m0 + wm * 32 + i * 16 + quad * 4 + r;
                dout[orow * H + ocol] = ac[i][j][r] + dbv + predf[orow * H + ocol];
            }
    }
}

// ---------------- fallbacks (ws too small): direct-global GEMMs ----------
__device__ inline bf16x8 ldb32(const void* p, long off) {
    const float* f = (const float*)p + off;
    const float4 a = *(const float4*)f;
    const float4 b = *(const float4*)(f + 4);
    bf16x8 r;
    r[0] = bfbits(a.x); r[1] = bfbits(a.y); r[2] = bfbits(a.z); r[3] = bfbits(a.w);
    r[4] = bfbits(b.x); r[5] = bfbits(b.y); r[6] = bfbits(b.z); r[7] = bfbits(b.w);
    return r;
}

__global__ __launch_bounds__(256) void k_gateup2(
    const __hip_bfloat16* __restrict__ predh,
    const void* __restrict__ gw, const float* __restrict__ gb,
    const void* __restrict__ uw, const float* __restrict__ ub,
    __hip_bfloat16* __restrict__ hid)
{
    const int wid = threadIdx.x >> 6, lane = threadIdx.x & 63;
    const int r16 = lane & 15, quad = lane >> 4;
    const int m0 = blockIdx.y * 64;
    const int n0 = blockIdx.x * 64 + wid * 16;

    f32x4 ag[4], au[4];
#pragma unroll
    for (int i = 0; i < 4; ++i) { ag[i] = (f32x4){0,0,0,0}; au[i] = (f32x4){0,0,0,0}; }
    const short* A = (const short*)predh;
    const long brow = (long)(n0 + r16) * H;

    for (int k0 = 0; k0 < H; k0 += 32) {
        const int k = k0 + quad * 8;
        const bf16x8 bg = ldb32(gw, brow + k);
        const bf16x8 bu = ldb32(uw, brow + k);
#pragma unroll
        for (int i = 0; i < 4; ++i) {
            const bf16x8 af = *(const bf16x8*)(A + (m0 + i * 16 + r16) * H + k);
            ag[i] = __builtin_amdgcn_mfma_f32_16x16x32_bf16(af, bg, ag[i], 0, 0, 0);
            au[i] = __builtin_amdgcn_mfma_f32_16x16x32_bf16(af, bu, au[i], 0, 0, 0);
        }
    }
    const int ocol = n0 + r16;
    const float gbv = gb[ocol], ubv = ub[ocol];
#pragma unroll
    for (int i = 0; i < 4; ++i)
#pragma unroll
        for (int r = 0; r < 4; ++r) {
            const int orow = m0 + i * 16 + quad * 4 + r;
            const float gg = ag[i][r] + gbv;
            const float u = au[i][r] + ubv;
            const float sg = 1.f / (1.f + __expf(-gg));
            hid[orow * H4 + ocol] = __float2bfloat16(sg * u);
        }
}

__global__ __launch_bounds__(256) void k_down2f(
    const __hip_bfloat16* __restrict__ hid,
    const void* __restrict__ dw, const float* __restrict__ db,
    const float* __restrict__ predf, float* __restrict__ dout)
{
    const int wid = threadIdx.x >> 6, lane = threadIdx.x & 63;
    const int r16 = lane & 15, quad = lane >> 4;
    const int m0 = blockIdx.y * 32;
    const int n0 = blockIdx.x * 64 + wid * 16;

    f32x4 ac[2];
    ac[0] = (f32x4){0,0,0,0}; ac[1] = (f32x4){0,0,0,0};
    const short* A = (const short*)hid;
    const long brow = (long)(n0 + r16) * H4;

    for (int k0 = 0; k0 < H4; k0 += 32) {
        const int k = k0 + quad * 8;
        const bf16x8 bd = ldb32(dw, brow + k);
#pragma unroll
        for (int i = 0; i < 2; ++i) {
            const bf16x8 af = *(const bf16x8*)(A + (m0 + i * 16 + r16) * H4 + k);
            ac[i] = __builtin_amdgcn_mfma_f32_16x16x32_bf16(af, bd, ac[i], 0, 0, 0);
        }
    }
    const int ocol = n0 + r16;
    const float dbv = db[ocol];
#pragma unroll
    for (int i = 0; i < 2; ++i)
#pragma unroll
        for (int r = 0; r < 4; ++r) {
            const int orow = m0 + i * 16 + quad * 4 + r;
            dout[orow * H + ocol] = ac[i][r] + dbv + predf[orow * H + ocol];
        }
}

// ---------------- K_ln: row-wise LayerNorm -> f32 out ----------------
__global__ __launch_bounds__(256) void k_ln(
    const float* __restrict__ dout,
    const float* __restrict__ nw,
    const float* __restrict__ nb,
    float* __restrict__ out)
{
    const int m = blockIdx.x;
    const int tid = threadIdx.x;
    const float* rowp = dout + m * H;

    float v[3];
    float s = 0.f, s2 = 0.f;
#pragma unroll
    for (int j = 0; j < 3; ++j) {
        v[j] = rowp[tid + 256 * j];
        s += v[j];
        s2 += v[j] * v[j];
    }
#pragma unroll
    for (int off = 32; off >= 1; off >>= 1) {
        s  += __shfl_xor(s, off, 64);
        s2 += __shfl_xor(s2, off, 64);
    }
    __shared__ float rs[4], rs2[4];
    const int wid = tid >> 6, lane = tid & 63;
    if (lane == 0) { rs[wid] = s; rs2[wid] = s2; }
    __syncthreads();
    s  = rs[0] + rs[1] + rs[2] + rs[3];
    s2 = rs2[0] + rs2[1] + rs2[2] + rs2[3];
    const float mu  = s / (float)H;
    const float var = s2 / (float)H - mu * mu;
    const float inv = rsqrtf(var + 1e-5f);
#pragma unroll
    for (int j = 0; j < 3; ++j) {
        const int hh = tid + 256 * j;
        out[m * H + hh] = (v[j] - mu) * inv * nw[hh] + nb[hh];
    }
}

// ---------------- launch ----------------
extern "C" void kernel_launch(void* const* d_in, const int* in_sizes, int n_in,
                              void* d_out, int out_size, void* d_ws, size_t ws_size,
                              hipStream_t stream)
{
    const float* x   = (const float*)d_in[0];
    const float* W0  = (const float*)d_in[1];
    const float* b0  = (const float*)d_in[2];
    const float* gw  = (const float*)d_in[3];
    const float* gb  = (const float*)d_in[4];
    const float* uw  = (const float*)d_in[5];
    const float* ub  = (const float*)d_in[6];
    const float* dw  = (const float*)d_in[7];
    const float* db  = (const float*)d_in[8];
    const float* nw  = (const float*)d_in[9];
    const float* nb  = (const float*)d_in[10];

    char* ws = (char*)d_ws;
    float*          pred_f = (float*)(ws);                       // 1,572,864
    __hip_bfloat16* pred_h = (__hip_bfloat16*)(ws + 1572864);    //   786,432
    __hip_bfloat16* hid    = (__hip_bfloat16*)(ws + 2359296);    // 3,145,728
    float*          base0  = (float*)(ws + 5505024);             // 1,572,864
    float*          dout_f = (float*)(ws + 5505024);             // alias: base0 dead before k_down3
    float*          g      = (float*)(ws + 7077888);             //   524,288
    short*          Xhi    = (short*)(ws + 7602176);             //   786,432
    short*          Xlo    = (short*)(ws + 8388608);             //   786,432
    short*          Whi    = (short*)(ws + 9175040);             // 1,179,648
    short*          Wlo    = (short*)(ws + 10354688);            // 1,179,648
    float*          U      = (float*)(ws + 11534336);            //   131,072
    const size_t WNEED = 11665408ULL + 3ULL * 4718592ULL;
    const bool wb = ws_size >= WNEED;
    short* gw2 = (short*)(ws + 11665408);
    short* uw2 = (short*)(ws + 11665408 + 4718592);
    short* dw2 = (short*)(ws + 11665408 + 2 * 4718592);

    const int ngroups = wb ? 2015232 : 245760;
    k_stage<<<dim3(ngroups / 256), 256, 0, stream>>>(
        x, W0, gw, uw, dw, Xhi, Xlo, Whi, Wlo, gw2, uw2, dw2);
    k_gram_base<<<dim3(128), 256, 0, stream>>>(Xhi, Xlo, Whi, Wlo, b0, g, base0);
    k_inv<<<dim3(BB * NC), 256, 0, stream>>>(g, U);
    k_recur4<<<dim3(96), 256, 0, stream>>>(x, base0, g, U, pred_f, pred_h);
    if (wb) {
        k_gateup3<<<dim3(H4 / 128, M / 64), 256, 0, stream>>>(pred_h, gw2, gb, uw2, ub, hid);
        k_down3<<<dim3(H / 64, M / 64), 256, 0, stream>>>(hid, dw2, db, pred_f, dout_f);
    } else {
        k_gateup2<<<dim3(H4 / 64, M / 64), 256, 0, stream>>>(pred_h, gw, gb, uw, ub, hid);
        k_down2f<<<dim3(H / 64, M / 32), 256, 0, stream>>>(hid, dw, db, pred_f, dout_f);
    }
    k_ln<<<dim3(M), 256, 0, stream>>>(dout_f, nw, nb, (float*)d_out);
}

// Round 7
// 223.170 us; speedup vs baseline: 1.0680x; 1.0680x over previous
//
#include <hip/hip_runtime.h>
#include <hip/hip_bf16.h>

#define H   768
#define H4  3072
#define S   256
#define BB  2
#define M   (BB * S)          // 512 rows of (b,t)
#define LRC 0.01f
#define C   64                // chunk size
#define NC  (S / C)           // 4 chunks

typedef __attribute__((ext_vector_type(8))) short bf16x8;
typedef __attribute__((ext_vector_type(4))) float f32x4;

__device__ inline short bfbits(float f) {
    __hip_bfloat16 h = __float2bfloat16(f);
    return *reinterpret_cast<short*>(&h);
}

// ---------------- K_stage: all input staging in ONE kernel ----------------
__global__ __launch_bounds__(256) void k_stage(
    const float* __restrict__ x,  const float* __restrict__ W0,
    const float* __restrict__ gw, const float* __restrict__ uw,
    const float* __restrict__ dw,
    short* __restrict__ Xhi, short* __restrict__ Xlo,
    short* __restrict__ Whi, short* __restrict__ Wlo,
    short* __restrict__ gw2, short* __restrict__ uw2, short* __restrict__ dw2)
{
    const long gid = (long)blockIdx.x * 256 + threadIdx.x;
    const float* src; short* hp; short* lp = nullptr; long base;
    if (gid < 98304)        { src = x;  hp = Xhi; lp = Xlo; base = 0; }
    else if (gid < 245760)  { src = W0; hp = Whi; lp = Wlo; base = 98304; }
    else if (gid < 835584)  { src = gw; hp = gw2; base = 245760; }
    else if (gid < 1425408) { src = uw; hp = uw2; base = 835584; }
    else                    { src = dw; hp = dw2; base = 1425408; }
    const long i = (gid - base) * 4;
    const float4 v = *(const float4*)(src + i);
    const float vf[4] = {v.x, v.y, v.z, v.w};
    short h4[4], l4[4];
#pragma unroll
    for (int j = 0; j < 4; ++j) {
        h4[j] = bfbits(vf[j]);
        __hip_bfloat16 hb = *reinterpret_cast<__hip_bfloat16*>(&h4[j]);
        l4[j] = bfbits(vf[j] - __bfloat162float(hb));
    }
    *(uint2*)(hp + i) = *(uint2*)h4;
    if (lp) *(uint2*)(lp + i) = *(uint2*)l4;
}

// ---------------- K_gram_base: merged Gram + Base0 GEMMs ------------------
__global__ __launch_bounds__(256) void k_gram_base(
    const short* __restrict__ Xhi, const short* __restrict__ Xlo,
    const short* __restrict__ Whi, const short* __restrict__ Wlo,
    const float* __restrict__ b0,
    float* __restrict__ g, float* __restrict__ base0)
{
    const int wid = threadIdx.x >> 6, lane = threadIdx.x & 63;
    const int r16 = lane & 15, quad = lane >> 4;
    const int id = blockIdx.x;

    f32x4 acc[4];
#pragma unroll
    for (int i = 0; i < 4; ++i) acc[i] = (f32x4){0, 0, 0, 0};

    if (id < 32) {  // ---- gram ----
        const int bx = id & 3, by = (id >> 2) & 3, b = id >> 4;
        const int m0 = by * 64, n0 = bx * 64 + wid * 16;
        const short* XH = Xhi + b * S * H;
        const short* XL = Xlo + b * S * H;
        for (int k0 = 0; k0 < H; k0 += 32) {
            const int k = k0 + quad * 8;
            const bf16x8 bh = *(const bf16x8*)(XH + (n0 + r16) * H + k);
            const bf16x8 bl = *(const bf16x8*)(XL + (n0 + r16) * H + k);
#pragma unroll
            for (int i = 0; i < 4; ++i) {
                const bf16x8 ah = *(const bf16x8*)(XH + (m0 + i * 16 + r16) * H + k);
                const bf16x8 al = *(const bf16x8*)(XL + (m0 + i * 16 + r16) * H + k);
                acc[i] = __builtin_amdgcn_mfma_f32_16x16x32_bf16(ah, bh, acc[i], 0, 0, 0);
                acc[i] = __builtin_amdgcn_mfma_f32_16x16x32_bf16(ah, bl, acc[i], 0, 0, 0);
                acc[i] = __builtin_amdgcn_mfma_f32_16x16x32_bf16(al, bh, acc[i], 0, 0, 0);
            }
        }
        const int col = n0 + r16;
#pragma unroll
        for (int i = 0; i < 4; ++i)
#pragma unroll
            for (int r = 0; r < 4; ++r) {
                const int row = m0 + i * 16 + quad * 4 + r;
                g[(b * S + row) * S + col] = acc[i][r] + 1.f;
            }
    } else {        // ---- base ----
        const int id2 = id - 32;
        const int m0 = (id2 / 12) * 64, n0 = (id2 % 12) * 64 + wid * 16;
        for (int k0 = 0; k0 < H; k0 += 32) {
            const int k = k0 + quad * 8;
            const bf16x8 bh = *(const bf16x8*)(Whi + (n0 + r16) * H + k);
            const bf16x8 bl = *(const bf16x8*)(Wlo + (n0 + r16) * H + k);
#pragma unroll
            for (int i = 0; i < 4; ++i) {
                const bf16x8 ah = *(const bf16x8*)(Xhi + (m0 + i * 16 + r16) * H + k);
                const bf16x8 al = *(const bf16x8*)(Xlo + (m0 + i * 16 + r16) * H + k);
                acc[i] = __builtin_amdgcn_mfma_f32_16x16x32_bf16(ah, bh, acc[i], 0, 0, 0);
                acc[i] = __builtin_amdgcn_mfma_f32_16x16x32_bf16(ah, bl, acc[i], 0, 0, 0);
                acc[i] = __builtin_amdgcn_mfma_f32_16x16x32_bf16(al, bh, acc[i], 0, 0, 0);
            }
        }
        const int col = n0 + r16;
        const float bv = b0[col];
#pragma unroll
        for (int i = 0; i < 4; ++i)
#pragma unroll
            for (int r = 0; r < 4; ++r) {
                const int row = m0 + i * 16 + quad * 4 + r;
                base0[row * H + col] = acc[i][r] + bv;
            }
    }
}

// ---------------- K_inv: U_c = T_c^{-1} for each (b, chunk) ---------------
__global__ __launch_bounds__(256) void k_inv(
    const float* __restrict__ g, float* __restrict__ U)
{
    __shared__ float Gi[C * 65];
    const int tid = threadIdx.x;
    const int w = tid >> 6, lane = tid & 63;
    const int b = blockIdx.x >> 2, c = blockIdx.x & 3;
    const int t0 = c * C;

#pragma unroll
    for (int j = 0; j < 16; ++j) {
        const int idx = tid + 256 * j;
        const int row = idx >> 6, col = idx & 63;
        Gi[row * 65 + col] = g[(long)(b * S + t0 + row) * S + t0 + col];
    }
    __syncthreads();

    const int j0 = w * 16;
    float R[16];
#pragma unroll
    for (int i = 0; i < 16; ++i) R[i] = (lane == j0 + i) ? 1.f : 0.f;

    for (int s = 0; s < C - 1; ++s) {
        const float Gv = Gi[s * 65 + lane];
        const float mlt = (lane > s) ? LRC : 0.f;
#pragma unroll
        for (int i = 0; i < 16; ++i) {
            const float dsb = __shfl(R[i], s, 64);
            R[i] -= mlt * Gv * dsb;
        }
    }
    float* Ub = U + (long)(b * NC + c) * C * C;
#pragma unroll
    for (int i = 0; i < 16; ++i)
        Ub[lane * C + j0 + i] = R[i];
}

// ---------------- K_recur5: solve via U; cross-chunk G staged in LDS -----
__global__ __launch_bounds__(256) void k_recur5(
    const float* __restrict__ x,
    const float* __restrict__ base0,
    const float* __restrict__ g,
    const float* __restrict__ U,
    float* __restrict__ pred_f,
    __hip_bfloat16* __restrict__ pred_h)
{
    __shared__ float tB[64 * 17];
    __shared__ float tX[64 * 17];
    __shared__ float Dl[256 * 17];
    __shared__ float Us[64 * 65];
    __shared__ float Gslab[192 * 64];    // cross-chunk G rows (48 KB max)
    const int tid = threadIdx.x;
    const int w = tid >> 6, lane = tid & 63;
    const int b = blockIdx.x / 48, hb = blockIdx.x % 48;
    const int h0 = hb * 16;
    const int ho = w * 4;
    const int ct = tid >> 2;
    const int cq = (tid & 3) * 4;

    for (int c = 0; c < NC; ++c) {
        const int t0 = c * C;
        __syncthreads();
        {   // stage tB = Base0 - Xn, tX = Xn, Us = U_c, Gslab = G[0:t0][t0+.]
            const int gm = b * S + t0 + ct;
            const float4 bv = *(const float4*)(base0 + gm * H + h0 + cq);
            float4 xv = {0.f, 0.f, 0.f, 0.f};
            if (t0 + ct + 1 < S)
                xv = *(const float4*)(x + (gm + 1) * H + h0 + cq);
            tB[ct * 17 + cq + 0] = bv.x - xv.x;
            tB[ct * 17 + cq + 1] = bv.y - xv.y;
            tB[ct * 17 + cq + 2] = bv.z - xv.z;
            tB[ct * 17 + cq + 3] = bv.w - xv.w;
            tX[ct * 17 + cq + 0] = xv.x;
            tX[ct * 17 + cq + 1] = xv.y;
            tX[ct * 17 + cq + 2] = xv.z;
            tX[ct * 17 + cq + 3] = xv.w;
            const float* Ub = U + (long)(b * NC + c) * C * C;
#pragma unroll
            for (int j = 0; j < 16; ++j) {
                const int idx = tid + 256 * j;
                const int row = idx >> 6, col = idx & 63;
                Us[row * 65 + col] = Ub[row * C + col];
            }
            // bulk-stage the cross-chunk G slab: rows [0,t0), cols t0..t0+63
            const float* gb = g + (long)(b * S) * S + t0;
            for (int i = tid; i < t0 * 64; i += 256) {
                const int row = i >> 6, col = i & 63;
                Gslab[i] = gb[(long)row * S + col];
            }
        }
        __syncthreads();
        float R[4], Xn[4];
#pragma unroll
        for (int h = 0; h < 4; ++h) {
            R[h]  = tB[lane * 17 + ho + h];
            Xn[h] = tX[lane * 17 + ho + h];
        }
        // cross-chunk corrections: R[t] -= LR * G[cs, t0+t] * D[cs] (LDS)
#pragma unroll 4
        for (int cs = 0; cs < t0; ++cs) {
            const float Gv = Gslab[cs * 64 + lane];
            const float* dr = &Dl[cs * 17 + ho];
            R[0] -= LRC * Gv * dr[0];
            R[1] -= LRC * Gv * dr[1];
            R[2] -= LRC * Gv * dr[2];
            R[3] -= LRC * Gv * dr[3];
        }
        // D = U * R'  (broadcast-based, no serial dependency)
        float D[4] = {0.f, 0.f, 0.f, 0.f};
#pragma unroll 8
        for (int s = 0; s < C; ++s) {
            const float Gv = Us[lane * 65 + s];     // U[t=lane][s]
#pragma unroll
            for (int h = 0; h < 4; ++h) {
                const float dsb = __shfl(R[h], s, 64);
                D[h] += Gv * dsb;
            }
        }
#pragma unroll
        for (int h = 0; h < 4; ++h) Dl[(t0 + lane) * 17 + ho + h] = D[h];
        __syncthreads();
#pragma unroll
        for (int h = 0; h < 4; ++h) tB[lane * 17 + ho + h] = D[h] + Xn[h];
        __syncthreads();
        {
            const int gm = b * S + t0 + ct;
            float4 pv;
            pv.x = tB[ct * 17 + cq + 0];
            pv.y = tB[ct * 17 + cq + 1];
            pv.z = tB[ct * 17 + cq + 2];
            pv.w = tB[ct * 17 + cq + 3];
            *(float4*)(pred_f + gm * H + h0 + cq) = pv;
            short p4[4];
            p4[0] = bfbits(pv.x); p4[1] = bfbits(pv.y);
            p4[2] = bfbits(pv.z); p4[3] = bfbits(pv.w);
            *(uint2*)((short*)pred_h + gm * H + h0 + cq) = *(uint2*)p4;
        }
    }
}

// ---------------- K_gateup3: LDS-tiled fused gate+up GEMM ----------------
#define RS 40
__global__ __launch_bounds__(256) void k_gateup3(
    const __hip_bfloat16* __restrict__ predh,
    const short* __restrict__ gwp, const float* __restrict__ gb,
    const short* __restrict__ uwp, const float* __restrict__ ub,
    __hip_bfloat16* __restrict__ hid)
{
    __shared__ int4 smv[1600];           // 25600 B
    short* sm = (short*)smv;
    short* sA = sm;                      // 64  x RS
    short* sG = sm + 64 * RS;            // 128 x RS
    short* sU = sm + (64 + 128) * RS;    // 128 x RS

    const int tid = threadIdx.x;
    const int wid = tid >> 6, lane = tid & 63;
    const int r16 = lane & 15, quad = lane >> 4;
    const int wm = wid & 1, wn = wid >> 1;
    const int n0 = blockIdx.x * 128;
    const int m0 = blockIdx.y * 64;

    const int srow = tid >> 2;
    const int sch  = (tid & 3) * 8;
    const short* A = (const short*)predh;

    f32x4 ag[2][4], au[2][4];
#pragma unroll
    for (int i = 0; i < 2; ++i)
#pragma unroll
        for (int j = 0; j < 4; ++j) { ag[i][j] = (f32x4){0,0,0,0}; au[i][j] = (f32x4){0,0,0,0}; }

    int4 rA, rG0, rG1, rU0, rU1;
    {
        const int k = sch;
        rA  = *(const int4*)(A   + (m0 + srow) * H + k);
        rG0 = *(const int4*)(gwp + (n0 + srow) * H + k);
        rG1 = *(const int4*)(gwp + (n0 + 64 + srow) * H + k);
        rU0 = *(const int4*)(uwp + (n0 + srow) * H + k);
        rU1 = *(const int4*)(uwp + (n0 + 64 + srow) * H + k);
    }
    for (int it = 0; it < 24; ++it) {
        *(int4*)(sA + srow * RS + sch)        = rA;
        *(int4*)(sG + srow * RS + sch)        = rG0;
        *(int4*)(sG + (64 + srow) * RS + sch) = rG1;
        *(int4*)(sU + srow * RS + sch)        = rU0;
        *(int4*)(sU + (64 + srow) * RS + sch) = rU1;
        __syncthreads();
        if (it < 23) {
            const int k = (it + 1) * 32 + sch;
            rA  = *(const int4*)(A   + (m0 + srow) * H + k);
            rG0 = *(const int4*)(gwp + (n0 + srow) * H + k);
            rG1 = *(const int4*)(gwp + (n0 + 64 + srow) * H + k);
            rU0 = *(const int4*)(uwp + (n0 + srow) * H + k);
            rU1 = *(const int4*)(uwp + (n0 + 64 + srow) * H + k);
        }
        bf16x8 aF[2], gF[4], uF[4];
#pragma unroll
        for (int i = 0; i < 2; ++i)
            aF[i] = *(const bf16x8*)(sA + (wm * 32 + i * 16 + r16) * RS + quad * 8);
#pragma unroll
        for (int j = 0; j < 4; ++j) {
            gF[j] = *(const bf16x8*)(sG + (wn * 64 + j * 16 + r16) * RS + quad * 8);
            uF[j] = *(const bf16x8*)(sU + (wn * 64 + j * 16 + r16) * RS + quad * 8);
        }
#pragma unroll
        for (int i = 0; i < 2; ++i)
#pragma unroll
            for (int j = 0; j < 4; ++j) {
                ag[i][j] = __builtin_amdgcn_mfma_f32_16x16x32_bf16(aF[i], gF[j], ag[i][j], 0, 0, 0);
                au[i][j] = __builtin_amdgcn_mfma_f32_16x16x32_bf16(aF[i], uF[j], au[i][j], 0, 0, 0);
            }
        __syncthreads();
    }
#pragma unroll
    for (int j = 0; j < 4; ++j) {
        const int ocol = n0 + wn * 64 + j * 16 + r16;
        const float gbv = gb[ocol], ubv = ub[ocol];
#pragma unroll
        for (int i = 0; i < 2; ++i)
#pragma unroll
            for (int r = 0; r < 4; ++r) {
                const int orow = m0 + wm * 32 + i * 16 + quad * 4 + r;
                const float gg = ag[i][j][r] + gbv;
                const float u  = au[i][j][r] + ubv;
                const float sg = 1.f / (1.f + __expf(-gg));
                hid[orow * H4 + ocol] = __float2bfloat16(sg * u);
            }
    }
}

// ---------------- K_down2b: direct-global down GEMM + bias + residual ----
__device__ inline bf16x8 ldb16(const void* p, long off) {
    return *(const bf16x8*)((const short*)p + off);
}
__global__ __launch_bounds__(256) void k_down2b(
    const __hip_bfloat16* __restrict__ hid,
    const short* __restrict__ dwp, const float* __restrict__ db,
    const float* __restrict__ predf, float* __restrict__ dout)
{
    const int wid = threadIdx.x >> 6, lane = threadIdx.x & 63;
    const int r16 = lane & 15, quad = lane >> 4;
    const int m0 = blockIdx.y * 32;
    const int n0 = blockIdx.x * 64 + wid * 16;

    f32x4 ac[2];
    ac[0] = (f32x4){0,0,0,0}; ac[1] = (f32x4){0,0,0,0};
    const short* A = (const short*)hid;
    const long brow = (long)(n0 + r16) * H4;

    for (int k0 = 0; k0 < H4; k0 += 32) {
        const int k = k0 + quad * 8;
        const bf16x8 bd = ldb16(dwp, brow + k);
#pragma unroll
        for (int i = 0; i < 2; ++i) {
            const bf16x8 af = *(const bf16x8*)(A + (m0 + i * 16 + r16) * H4 + k);
            ac[i] = __builtin_amdgcn_mfma_f32_16x16x32_bf16(af, bd, ac[i], 0, 0, 0);
        }
    }
    const int ocol = n0 + r16;
    const float dbv = db[ocol];
#pragma unroll
    for (int i = 0; i < 2; ++i)
#pragma unroll
        for (int r = 0; r < 4; ++r) {
            const int orow = m0 + i * 16 + quad * 4 + r;
            dout[orow * H + ocol] = ac[i][r] + dbv + predf[orow * H + ocol];
        }
}

// ---------------- fallbacks (ws too small): direct-global f32 GEMMs ------
__device__ inline bf16x8 ldb32(const void* p, long off) {
    const float* f = (const float*)p + off;
    const float4 a = *(const float4*)f;
    const float4 b = *(const float4*)(f + 4);
    bf16x8 r;
    r[0] = bfbits(a.x); r[1] = bfbits(a.y); r[2] = bfbits(a.z); r[3] = bfbits(a.w);
    r[4] = bfbits(b.x); r[5] = bfbits(b.y); r[6] = bfbits(b.z); r[7] = bfbits(b.w);
    return r;
}

__global__ __launch_bounds__(256) void k_gateup2(
    const __hip_bfloat16* __restrict__ predh,
    const void* __restrict__ gw, const float* __restrict__ gb,
    const void* __restrict__ uw, const float* __restrict__ ub,
    __hip_bfloat16* __restrict__ hid)
{
    const int wid = threadIdx.x >> 6, lane = threadIdx.x & 63;
    const int r16 = lane & 15, quad = lane >> 4;
    const int m0 = blockIdx.y * 64;
    const int n0 = blockIdx.x * 64 + wid * 16;

    f32x4 ag[4], au[4];
#pragma unroll
    for (int i = 0; i < 4; ++i) { ag[i] = (f32x4){0,0,0,0}; au[i] = (f32x4){0,0,0,0}; }
    const short* A = (const short*)predh;
    const long brow = (long)(n0 + r16) * H;

    for (int k0 = 0; k0 < H; k0 += 32) {
        const int k = k0 + quad * 8;
        const bf16x8 bg = ldb32(gw, brow + k);
        const bf16x8 bu = ldb32(uw, brow + k);
#pragma unroll
        for (int i = 0; i < 4; ++i) {
            const bf16x8 af = *(const bf16x8*)(A + (m0 + i * 16 + r16) * H + k);
            ag[i] = __builtin_amdgcn_mfma_f32_16x16x32_bf16(af, bg, ag[i], 0, 0, 0);
            au[i] = __builtin_amdgcn_mfma_f32_16x16x32_bf16(af, bu, au[i], 0, 0, 0);
        }
    }
    const int ocol = n0 + r16;
    const float gbv = gb[ocol], ubv = ub[ocol];
#pragma unroll
    for (int i = 0; i < 4; ++i)
#pragma unroll
        for (int r = 0; r < 4; ++r) {
            const int orow = m0 + i * 16 + quad * 4 + r;
            const float gg = ag[i][r] + gbv;
            const float u = au[i][r] + ubv;
            const float sg = 1.f / (1.f + __expf(-gg));
            hid[orow * H4 + ocol] = __float2bfloat16(sg * u);
        }
}

__global__ __launch_bounds__(256) void k_down2f(
    const __hip_bfloat16* __restrict__ hid,
    const void* __restrict__ dw, const float* __restrict__ db,
    const float* __restrict__ predf, float* __restrict__ dout)
{
    const int wid = threadIdx.x >> 6, lane = threadIdx.x & 63;
    const int r16 = lane & 15, quad = lane >> 4;
    const int m0 = blockIdx.y * 32;
    const int n0 = blockIdx.x * 64 + wid * 16;

    f32x4 ac[2];
    ac[0] = (f32x4){0,0,0,0}; ac[1] = (f32x4){0,0,0,0};
    const short* A = (const short*)hid;
    const long brow = (long)(n0 + r16) * H4;

    for (int k0 = 0; k0 < H4; k0 += 32) {
        const int k = k0 + quad * 8;
        const bf16x8 bd = ldb32(dw, brow + k);
#pragma unroll
        for (int i = 0; i < 2; ++i) {
            const bf16x8 af = *(const bf16x8*)(A + (m0 + i * 16 + r16) * H4 + k);
            ac[i] = __builtin_amdgcn_mfma_f32_16x16x32_bf16(af, bd, ac[i], 0, 0, 0);
        }
    }
    const int ocol = n0 + r16;
    const float dbv = db[ocol];
#pragma unroll
    for (int i = 0; i < 2; ++i)
#pragma unroll
        for (int r = 0; r < 4; ++r) {
            const int orow = m0 + i * 16 + quad * 4 + r;
            dout[orow * H + ocol] = ac[i][r] + dbv + predf[orow * H + ocol];
        }
}

// ---------------- K_ln: row-wise LayerNorm -> f32 out ----------------
__global__ __launch_bounds__(256) void k_ln(
    const float* __restrict__ dout,
    const float* __restrict__ nw,
    const float* __restrict__ nb,
    float* __restrict__ out)
{
    const int m = blockIdx.x;
    const int tid = threadIdx.x;
    const float* rowp = dout + m * H;

    float v[3];
    float s = 0.f, s2 = 0.f;
#pragma unroll
    for (int j = 0; j < 3; ++j) {
        v[j] = rowp[tid + 256 * j];
        s += v[j];
        s2 += v[j] * v[j];
    }
#pragma unroll
    for (int off = 32; off >= 1; off >>= 1) {
        s  += __shfl_xor(s, off, 64);
        s2 += __shfl_xor(s2, off, 64);
    }
    __shared__ float rs[4], rs2[4];
    const int wid = tid >> 6, lane = tid & 63;
    if (lane == 0) { rs[wid] = s; rs2[wid] = s2; }
    __syncthreads();
    s  = rs[0] + rs[1] + rs[2] + rs[3];
    s2 = rs2[0] + rs2[1] + rs2[2] + rs2[3];
    const float mu  = s / (float)H;
    const float var = s2 / (float)H - mu * mu;
    const float inv = rsqrtf(var + 1e-5f);
#pragma unroll
    for (int j = 0; j < 3; ++j) {
        const int hh = tid + 256 * j;
        out[m * H + hh] = (v[j] - mu) * inv * nw[hh] + nb[hh];
    }
}

// ---------------- launch ----------------
extern "C" void kernel_launch(void* const* d_in, const int* in_sizes, int n_in,
                              void* d_out, int out_size, void* d_ws, size_t ws_size,
                              hipStream_t stream)
{
    const float* x   = (const float*)d_in[0];
    const float* W0  = (const float*)d_in[1];
    const float* b0  = (const float*)d_in[2];
    const float* gw  = (const float*)d_in[3];
    const float* gb  = (const float*)d_in[4];
    const float* uw  = (const float*)d_in[5];
    const float* ub  = (const float*)d_in[6];
    const float* dw  = (const float*)d_in[7];
    const float* db  = (const float*)d_in[8];
    const float* nw  = (const float*)d_in[9];
    const float* nb  = (const float*)d_in[10];

    char* ws = (char*)d_ws;
    float*          pred_f = (float*)(ws);                       // 1,572,864
    __hip_bfloat16* pred_h = (__hip_bfloat16*)(ws + 1572864);    //   786,432
    __hip_bfloat16* hid    = (__hip_bfloat16*)(ws + 2359296);    // 3,145,728
    float*          base0  = (float*)(ws + 5505024);             // 1,572,864
    float*          dout_f = (float*)(ws + 5505024);             // alias: base0 dead before k_down
    float*          g      = (float*)(ws + 7077888);             //   524,288
    short*          Xhi    = (short*)(ws + 7602176);             //   786,432
    short*          Xlo    = (short*)(ws + 8388608);             //   786,432
    short*          Whi    = (short*)(ws + 9175040);             // 1,179,648
    short*          Wlo    = (short*)(ws + 10354688);            // 1,179,648
    float*          U      = (float*)(ws + 11534336);            //   131,072
    const size_t WNEED = 11665408ULL + 3ULL * 4718592ULL;
    const bool wb = ws_size >= WNEED;
    short* gw2 = (short*)(ws + 11665408);
    short* uw2 = (short*)(ws + 11665408 + 4718592);
    short* dw2 = (short*)(ws + 11665408 + 2 * 4718592);

    const int ngroups = wb ? 2015232 : 245760;
    k_stage<<<dim3(ngroups / 256), 256, 0, stream>>>(
        x, W0, gw, uw, dw, Xhi, Xlo, Whi, Wlo, gw2, uw2, dw2);
    k_gram_base<<<dim3(128), 256, 0, stream>>>(Xhi, Xlo, Whi, Wlo, b0, g, base0);
    k_inv<<<dim3(BB * NC), 256, 0, stream>>>(g, U);
    k_recur5<<<dim3(96), 256, 0, stream>>>(x, base0, g, U, pred_f, pred_h);
    if (wb) {
        k_gateup3<<<dim3(H4 / 128, M / 64), 256, 0, stream>>>(pred_h, gw2, gb, uw2, ub, hid);
        k_down2b<<<dim3(H / 64, M / 32), 256, 0, stream>>>(hid, dw2, db, pred_f, dout_f);
    } else {
        k_gateup2<<<dim3(H4 / 64, M / 64), 256, 0, stream>>>(pred_h, gw, gb, uw, ub, hid);
        k_down2f<<<dim3(H / 64, M / 32), 256, 0, stream>>>(hid, dw, db, pred_f, dout_f);
    }
    k_ln<<<dim3(M), 256, 0, stream>>>(dout_f, nw, nb, (float*)d_out);
}

// Round 8
// 205.822 us; speedup vs baseline: 1.1580x; 1.0843x over previous
//
#include <hip/hip_runtime.h>
#include <hip/hip_bf16.h>

#define H   768
#define H4  3072
#define S   256
#define BB  2
#define M   (BB * S)          // 512 rows of (b,t)
#define LRC 0.01f
#define C   64                // chunk size
#define NC  (S / C)           // 4 chunks

typedef __attribute__((ext_vector_type(8))) short bf16x8;
typedef __attribute__((ext_vector_type(4))) float f32x4;

__device__ inline short bfbits(float f) {
    __hip_bfloat16 h = __float2bfloat16(f);
    return *reinterpret_cast<short*>(&h);
}

// ---------------- K_stage: all input staging in ONE kernel ----------------
__global__ __launch_bounds__(256) void k_stage(
    const float* __restrict__ x,  const float* __restrict__ W0,
    const float* __restrict__ gw, const float* __restrict__ uw,
    const float* __restrict__ dw,
    short* __restrict__ Xhi, short* __restrict__ Xlo,
    short* __restrict__ Whi, short* __restrict__ Wlo,
    short* __restrict__ gw2, short* __restrict__ uw2, short* __restrict__ dw2)
{
    const long gid = (long)blockIdx.x * 256 + threadIdx.x;
    const float* src; short* hp; short* lp = nullptr; long base;
    if (gid < 98304)        { src = x;  hp = Xhi; lp = Xlo; base = 0; }
    else if (gid < 245760)  { src = W0; hp = Whi; lp = Wlo; base = 98304; }
    else if (gid < 835584)  { src = gw; hp = gw2; base = 245760; }
    else if (gid < 1425408) { src = uw; hp = uw2; base = 835584; }
    else                    { src = dw; hp = dw2; base = 1425408; }
    const long i = (gid - base) * 4;
    const float4 v = *(const float4*)(src + i);
    const float vf[4] = {v.x, v.y, v.z, v.w};
    short h4[4], l4[4];
#pragma unroll
    for (int j = 0; j < 4; ++j) {
        h4[j] = bfbits(vf[j]);
        __hip_bfloat16 hb = *reinterpret_cast<__hip_bfloat16*>(&h4[j]);
        l4[j] = bfbits(vf[j] - __bfloat162float(hb));
    }
    *(uint2*)(hp + i) = *(uint2*)h4;
    if (lp) *(uint2*)(lp + i) = *(uint2*)l4;
}

// ---------------- K_gram_base: merged Gram + Base0 GEMMs ------------------
__global__ __launch_bounds__(256) void k_gram_base(
    const short* __restrict__ Xhi, const short* __restrict__ Xlo,
    const short* __restrict__ Whi, const short* __restrict__ Wlo,
    const float* __restrict__ b0,
    float* __restrict__ g, float* __restrict__ base0)
{
    const int wid = threadIdx.x >> 6, lane = threadIdx.x & 63;
    const int r16 = lane & 15, quad = lane >> 4;
    const int id = blockIdx.x;

    f32x4 acc[4];
#pragma unroll
    for (int i = 0; i < 4; ++i) acc[i] = (f32x4){0, 0, 0, 0};

    if (id < 32) {  // ---- gram ----
        const int bx = id & 3, by = (id >> 2) & 3, b = id >> 4;
        const int m0 = by * 64, n0 = bx * 64 + wid * 16;
        const short* XH = Xhi + b * S * H;
        const short* XL = Xlo + b * S * H;
        for (int k0 = 0; k0 < H; k0 += 32) {
            const int k = k0 + quad * 8;
            const bf16x8 bh = *(const bf16x8*)(XH + (n0 + r16) * H + k);
            const bf16x8 bl = *(const bf16x8*)(XL + (n0 + r16) * H + k);
#pragma unroll
            for (int i = 0; i < 4; ++i) {
                const bf16x8 ah = *(const bf16x8*)(XH + (m0 + i * 16 + r16) * H + k);
                const bf16x8 al = *(const bf16x8*)(XL + (m0 + i * 16 + r16) * H + k);
                acc[i] = __builtin_amdgcn_mfma_f32_16x16x32_bf16(ah, bh, acc[i], 0, 0, 0);
                acc[i] = __builtin_amdgcn_mfma_f32_16x16x32_bf16(ah, bl, acc[i], 0, 0, 0);
                acc[i] = __builtin_amdgcn_mfma_f32_16x16x32_bf16(al, bh, acc[i], 0, 0, 0);
            }
        }
        const int col = n0 + r16;
#pragma unroll
        for (int i = 0; i < 4; ++i)
#pragma unroll
            for (int r = 0; r < 4; ++r) {
                const int row = m0 + i * 16 + quad * 4 + r;
                g[(b * S + row) * S + col] = acc[i][r] + 1.f;
            }
    } else {        // ---- base ----
        const int id2 = id - 32;
        const int m0 = (id2 / 12) * 64, n0 = (id2 % 12) * 64 + wid * 16;
        for (int k0 = 0; k0 < H; k0 += 32) {
            const int k = k0 + quad * 8;
            const bf16x8 bh = *(const bf16x8*)(Whi + (n0 + r16) * H + k);
            const bf16x8 bl = *(const bf16x8*)(Wlo + (n0 + r16) * H + k);
#pragma unroll
            for (int i = 0; i < 4; ++i) {
                const bf16x8 ah = *(const bf16x8*)(Xhi + (m0 + i * 16 + r16) * H + k);
                const bf16x8 al = *(const bf16x8*)(Xlo + (m0 + i * 16 + r16) * H + k);
                acc[i] = __builtin_amdgcn_mfma_f32_16x16x32_bf16(ah, bh, acc[i], 0, 0, 0);
                acc[i] = __builtin_amdgcn_mfma_f32_16x16x32_bf16(ah, bl, acc[i], 0, 0, 0);
                acc[i] = __builtin_amdgcn_mfma_f32_16x16x32_bf16(al, bh, acc[i], 0, 0, 0);
            }
        }
        const int col = n0 + r16;
        const float bv = b0[col];
#pragma unroll
        for (int i = 0; i < 4; ++i)
#pragma unroll
            for (int r = 0; r < 4; ++r) {
                const int row = m0 + i * 16 + quad * 4 + r;
                base0[row * H + col] = acc[i][r] + bv;
            }
    }
}

// ---------------- K_inv: U_c = T_c^{-1} for each (b, chunk) ---------------
__global__ __launch_bounds__(256) void k_inv(
    const float* __restrict__ g, float* __restrict__ U)
{
    __shared__ float Gi[C * 65];
    const int tid = threadIdx.x;
    const int w = tid >> 6, lane = tid & 63;
    const int b = blockIdx.x >> 2, c = blockIdx.x & 3;
    const int t0 = c * C;

#pragma unroll
    for (int j = 0; j < 16; ++j) {
        const int idx = tid + 256 * j;
        const int row = idx >> 6, col = idx & 63;
        Gi[row * 65 + col] = g[(long)(b * S + t0 + row) * S + t0 + col];
    }
    __syncthreads();

    const int j0 = w * 16;
    float R[16];
#pragma unroll
    for (int i = 0; i < 16; ++i) R[i] = (lane == j0 + i) ? 1.f : 0.f;

    for (int s = 0; s < C - 1; ++s) {
        const float Gv = Gi[s * 65 + lane];
        const float mlt = (lane > s) ? LRC : 0.f;
#pragma unroll
        for (int i = 0; i < 16; ++i) {
            const float dsb = __shfl(R[i], s, 64);
            R[i] -= mlt * Gv * dsb;
        }
    }
    float* Ub = U + (long)(b * NC + c) * C * C;
#pragma unroll
    for (int i = 0; i < 16; ++i)
        Ub[lane * C + j0 + i] = R[i];
}

// ---------------- K_recur6: solve via U; no shuffles (LDS broadcast) -----
__global__ __launch_bounds__(256) void k_recur6(
    const float* __restrict__ x,
    const float* __restrict__ base0,
    const float* __restrict__ g,
    const float* __restrict__ U,
    float* __restrict__ pred_f,
    __hip_bfloat16* __restrict__ pred_h)
{
    __shared__ float  tB[64 * 17];
    __shared__ float  tX[64 * 17];
    __shared__ float4 Dl4[256 * 4];      // D history: row t, slot w (16 KB)
    __shared__ float4 Rl4[4 * 64];       // per-wave R vector (4 KB)
    __shared__ float  Us[64 * 65];
    __shared__ float  Gslab[192 * 64];   // cross-chunk G rows (48 KB max)
    const int tid = threadIdx.x;
    const int w = tid >> 6, lane = tid & 63;
    const int b = blockIdx.x / 48, hb = blockIdx.x % 48;
    const int h0 = hb * 16;
    const int ho = w * 4;
    const int ct = tid >> 2;
    const int cq = (tid & 3) * 4;

    for (int c = 0; c < NC; ++c) {
        const int t0 = c * C;
        __syncthreads();
        {   // stage tB = Base0 - Xn, tX = Xn, Us = U_c, Gslab = G[0:t0][t0+.]
            const int gm = b * S + t0 + ct;
            const float4 bv = *(const float4*)(base0 + gm * H + h0 + cq);
            float4 xv = {0.f, 0.f, 0.f, 0.f};
            if (t0 + ct + 1 < S)
                xv = *(const float4*)(x + (gm + 1) * H + h0 + cq);
            tB[ct * 17 + cq + 0] = bv.x - xv.x;
            tB[ct * 17 + cq + 1] = bv.y - xv.y;
            tB[ct * 17 + cq + 2] = bv.z - xv.z;
            tB[ct * 17 + cq + 3] = bv.w - xv.w;
            tX[ct * 17 + cq + 0] = xv.x;
            tX[ct * 17 + cq + 1] = xv.y;
            tX[ct * 17 + cq + 2] = xv.z;
            tX[ct * 17 + cq + 3] = xv.w;
            const float* Ub = U + (long)(b * NC + c) * C * C;
#pragma unroll
            for (int j = 0; j < 16; ++j) {
                const int idx = tid + 256 * j;
                const int row = idx >> 6, col = idx & 63;
                Us[row * 65 + col] = Ub[row * C + col];
            }
            const float* gb = g + (long)(b * S) * S + t0;
            for (int i = tid; i < t0 * 64; i += 256) {
                const int row = i >> 6, col = i & 63;
                Gslab[i] = gb[(long)row * S + col];
            }
        }
        __syncthreads();
        float R[4], Xn[4];
#pragma unroll
        for (int h = 0; h < 4; ++h) {
            R[h]  = tB[lane * 17 + ho + h];
            Xn[h] = tX[lane * 17 + ho + h];
        }
        // cross-chunk corrections (Dl4 slot w written by THIS wave in
        // earlier chunks -> same-wave dependency only, no barrier needed)
#pragma unroll 4
        for (int cs = 0; cs < t0; ++cs) {
            const float Gv = Gslab[cs * 64 + lane];
            const float4 dr = Dl4[cs * 4 + w];    // broadcast read
            R[0] -= LRC * Gv * dr.x;
            R[1] -= LRC * Gv * dr.y;
            R[2] -= LRC * Gv * dr.z;
            R[3] -= LRC * Gv * dr.w;
        }
        // publish R for this wave, then D[t] = sum_s U[t][s] * R[s]
        Rl4[w * 64 + lane] = (float4){R[0], R[1], R[2], R[3]};
        float D[4] = {0.f, 0.f, 0.f, 0.f};
#pragma unroll 8
        for (int s = 0; s < C; ++s) {
            const float4 rb = Rl4[w * 64 + s];    // broadcast read
            const float uv = Us[lane * 65 + s];   // U[t=lane][s]
            D[0] += uv * rb.x;
            D[1] += uv * rb.y;
            D[2] += uv * rb.z;
            D[3] += uv * rb.w;
        }
        Dl4[(t0 + lane) * 4 + w] = (float4){D[0], D[1], D[2], D[3]};
        __syncthreads();
#pragma unroll
        for (int h = 0; h < 4; ++h) tB[lane * 17 + ho + h] = D[h] + Xn[h];
        __syncthreads();
        {
            const int gm = b * S + t0 + ct;
            float4 pv;
            pv.x = tB[ct * 17 + cq + 0];
            pv.y = tB[ct * 17 + cq + 1];
            pv.z = tB[ct * 17 + cq + 2];
            pv.w = tB[ct * 17 + cq + 3];
            *(float4*)(pred_f + gm * H + h0 + cq) = pv;
            short p4[4];
            p4[0] = bfbits(pv.x); p4[1] = bfbits(pv.y);
            p4[2] = bfbits(pv.z); p4[3] = bfbits(pv.w);
            *(uint2*)((short*)pred_h + gm * H + h0 + cq) = *(uint2*)p4;
        }
    }
}

// ---------------- K_gateup4: LDS-tiled fused gate+up GEMM, 64x64 tiles ---
#define RS 40
__global__ __launch_bounds__(256) void k_gateup4(
    const __hip_bfloat16* __restrict__ predh,
    const short* __restrict__ gwp, const float* __restrict__ gb,
    const short* __restrict__ uwp, const float* __restrict__ ub,
    __hip_bfloat16* __restrict__ hid)
{
    __shared__ int4 smv[960];            // 15360 B
    short* sm = (short*)smv;
    short* sA = sm;                      // 64 x RS
    short* sG = sm + 64 * RS;            // 64 x RS
    short* sU = sm + 128 * RS;           // 64 x RS

    const int tid = threadIdx.x;
    const int wid = tid >> 6, lane = tid & 63;
    const int r16 = lane & 15, quad = lane >> 4;
    const int wm = wid & 1, wn = (wid >> 1) & 1;
    const int n0 = blockIdx.x * 64;
    const int m0 = blockIdx.y * 64;

    const int srow = tid >> 2;
    const int sch  = (tid & 3) * 8;
    const short* A = (const short*)predh;

    f32x4 ag[2][2], au[2][2];
#pragma unroll
    for (int i = 0; i < 2; ++i)
#pragma unroll
        for (int j = 0; j < 2; ++j) { ag[i][j] = (f32x4){0,0,0,0}; au[i][j] = (f32x4){0,0,0,0}; }

    int4 rA, rG, rU;
    rA = *(const int4*)(A   + (m0 + srow) * H + sch);
    rG = *(const int4*)(gwp + (n0 + srow) * H + sch);
    rU = *(const int4*)(uwp + (n0 + srow) * H + sch);
    for (int it = 0; it < 24; ++it) {
        *(int4*)(sA + srow * RS + sch) = rA;
        *(int4*)(sG + srow * RS + sch) = rG;
        *(int4*)(sU + srow * RS + sch) = rU;
        __syncthreads();
        if (it < 23) {
            const int k = (it + 1) * 32 + sch;
            rA = *(const int4*)(A   + (m0 + srow) * H + k);
            rG = *(const int4*)(gwp + (n0 + srow) * H + k);
            rU = *(const int4*)(uwp + (n0 + srow) * H + k);
        }
        bf16x8 aF[2], gF[2], uF[2];
#pragma unroll
        for (int i = 0; i < 2; ++i) {
            aF[i] = *(const bf16x8*)(sA + (wm * 32 + i * 16 + r16) * RS + quad * 8);
            gF[i] = *(const bf16x8*)(sG + (wn * 32 + i * 16 + r16) * RS + quad * 8);
            uF[i] = *(const bf16x8*)(sU + (wn * 32 + i * 16 + r16) * RS + quad * 8);
        }
#pragma unroll
        for (int i = 0; i < 2; ++i)
#pragma unroll
            for (int j = 0; j < 2; ++j) {
                ag[i][j] = __builtin_amdgcn_mfma_f32_16x16x32_bf16(aF[i], gF[j], ag[i][j], 0, 0, 0);
                au[i][j] = __builtin_amdgcn_mfma_f32_16x16x32_bf16(aF[i], uF[j], au[i][j], 0, 0, 0);
            }
        __syncthreads();
    }
#pragma unroll
    for (int j = 0; j < 2; ++j) {
        const int ocol = n0 + wn * 32 + j * 16 + r16;
        const float gbv = gb[ocol], ubv = ub[ocol];
#pragma unroll
        for (int i = 0; i < 2; ++i)
#pragma unroll
            for (int r = 0; r < 4; ++r) {
                const int orow = m0 + wm * 32 + i * 16 + quad * 4 + r;
                const float gg = ag[i][j][r] + gbv;
                const float u  = au[i][j][r] + ubv;
                const float sg = 1.f / (1.f + __expf(-gg));
                hid[orow * H4 + ocol] = __float2bfloat16(sg * u);
            }
    }
}

// ---------------- K_down4: split-K down GEMM -> f32 partials -------------
__device__ inline bf16x8 ldb16(const void* p, long off) {
    return *(const bf16x8*)((const short*)p + off);
}
__global__ __launch_bounds__(256) void k_down4(
    const __hip_bfloat16* __restrict__ hid,
    const short* __restrict__ dwp,
    float* __restrict__ dpart)
{
    const int wid = threadIdx.x >> 6, lane = threadIdx.x & 63;
    const int r16 = lane & 15, quad = lane >> 4;
    const int m0 = blockIdx.y * 32;
    const int n0 = blockIdx.x * 64 + wid * 16;
    const int kz = blockIdx.z;

    f32x4 ac[2];
    ac[0] = (f32x4){0,0,0,0}; ac[1] = (f32x4){0,0,0,0};
    const short* A = (const short*)hid;
    const long brow = (long)(n0 + r16) * H4;

    const int kbeg = kz * 768, kend = kbeg + 768;
    for (int k0 = kbeg; k0 < kend; k0 += 32) {
        const int k = k0 + quad * 8;
        const bf16x8 bd = ldb16(dwp, brow + k);
#pragma unroll
        for (int i = 0; i < 2; ++i) {
            const bf16x8 af = *(const bf16x8*)(A + (m0 + i * 16 + r16) * H4 + k);
            ac[i] = __builtin_amdgcn_mfma_f32_16x16x32_bf16(af, bd, ac[i], 0, 0, 0);
        }
    }
    float* dp = dpart + (long)kz * M * H;
    const int ocol = n0 + r16;
#pragma unroll
    for (int i = 0; i < 2; ++i)
#pragma unroll
        for (int r = 0; r < 4; ++r) {
            const int orow = m0 + i * 16 + quad * 4 + r;
            dp[orow * H + ocol] = ac[i][r];
        }
}

// ---------------- K_ln2: sum partials + bias + residual + LayerNorm ------
__global__ __launch_bounds__(256) void k_ln2(
    const float* __restrict__ dpart,
    const float* __restrict__ db,
    const float* __restrict__ predf,
    const float* __restrict__ nw,
    const float* __restrict__ nb,
    float* __restrict__ out)
{
    const int m = blockIdx.x;
    const int tid = threadIdx.x;

    float v[3];
    float s = 0.f, s2 = 0.f;
#pragma unroll
    for (int j = 0; j < 3; ++j) {
        const int hh = tid + 256 * j;
        const long o = (long)m * H + hh;
        float t = dpart[o] + dpart[o + (long)M * H]
                + dpart[o + 2L * M * H] + dpart[o + 3L * M * H]
                + db[hh] + predf[o];
        v[j] = t;
        s += t;
        s2 += t * t;
    }
#pragma unroll
    for (int off = 32; off >= 1; off >>= 1) {
        s  += __shfl_xor(s, off, 64);
        s2 += __shfl_xor(s2, off, 64);
    }
    __shared__ float rs[4], rs2[4];
    const int wid = tid >> 6, lane = tid & 63;
    if (lane == 0) { rs[wid] = s; rs2[wid] = s2; }
    __syncthreads();
    s  = rs[0] + rs[1] + rs[2] + rs[3];
    s2 = rs2[0] + rs2[1] + rs2[2] + rs2[3];
    const float mu  = s / (float)H;
    const float var = s2 / (float)H - mu * mu;
    const float inv = rsqrtf(var + 1e-5f);
#pragma unroll
    for (int j = 0; j < 3; ++j) {
        const int hh = tid + 256 * j;
        out[m * H + hh] = (v[j] - mu) * inv * nw[hh] + nb[hh];
    }
}

// ---------------- fallbacks (ws too small): direct-global f32 GEMMs ------
__device__ inline bf16x8 ldb32(const void* p, long off) {
    const float* f = (const float*)p + off;
    const float4 a = *(const float4*)f;
    const float4 b = *(const float4*)(f + 4);
    bf16x8 r;
    r[0] = bfbits(a.x); r[1] = bfbits(a.y); r[2] = bfbits(a.z); r[3] = bfbits(a.w);
    r[4] = bfbits(b.x); r[5] = bfbits(b.y); r[6] = bfbits(b.z); r[7] = bfbits(b.w);
    return r;
}

__global__ __launch_bounds__(256) void k_gateup2(
    const __hip_bfloat16* __restrict__ predh,
    const void* __restrict__ gw, const float* __restrict__ gb,
    const void* __restrict__ uw, const float* __restrict__ ub,
    __hip_bfloat16* __restrict__ hid)
{
    const int wid = threadIdx.x >> 6, lane = threadIdx.x & 63;
    const int r16 = lane & 15, quad = lane >> 4;
    const int m0 = blockIdx.y * 64;
    const int n0 = blockIdx.x * 64 + wid * 16;

    f32x4 ag[4], au[4];
#pragma unroll
    for (int i = 0; i < 4; ++i) { ag[i] = (f32x4){0,0,0,0}; au[i] = (f32x4){0,0,0,0}; }
    const short* A = (const short*)predh;
    const long brow = (long)(n0 + r16) * H;

    for (int k0 = 0; k0 < H; k0 += 32) {
        const int k = k0 + quad * 8;
        const bf16x8 bg = ldb32(gw, brow + k);
        const bf16x8 bu = ldb32(uw, brow + k);
#pragma unroll
        for (int i = 0; i < 4; ++i) {
            const bf16x8 af = *(const bf16x8*)(A + (m0 + i * 16 + r16) * H + k);
            ag[i] = __builtin_amdgcn_mfma_f32_16x16x32_bf16(af, bg, ag[i], 0, 0, 0);
            au[i] = __builtin_amdgcn_mfma_f32_16x16x32_bf16(af, bu, au[i], 0, 0, 0);
        }
    }
    const int ocol = n0 + r16;
    const float gbv = gb[ocol], ubv = ub[ocol];
#pragma unroll
    for (int i = 0; i < 4; ++i)
#pragma unroll
        for (int r = 0; r < 4; ++r) {
            const int orow = m0 + i * 16 + quad * 4 + r;
            const float gg = ag[i][r] + gbv;
            const float u = au[i][r] + ubv;
            const float sg = 1.f / (1.f + __expf(-gg));
            hid[orow * H4 + ocol] = __float2bfloat16(sg * u);
        }
}

__global__ __launch_bounds__(256) void k_down2f(
    const __hip_bfloat16* __restrict__ hid,
    const void* __restrict__ dw, const float* __restrict__ db,
    const float* __restrict__ predf, float* __restrict__ dout)
{
    const int wid = threadIdx.x >> 6, lane = threadIdx.x & 63;
    const int r16 = lane & 15, quad = lane >> 4;
    const int m0 = blockIdx.y * 32;
    const int n0 = blockIdx.x * 64 + wid * 16;

    f32x4 ac[2];
    ac[0] = (f32x4){0,0,0,0}; ac[1] = (f32x4){0,0,0,0};
    const short* A = (const short*)hid;
    const long brow = (long)(n0 + r16) * H4;

    for (int k0 = 0; k0 < H4; k0 += 32) {
        const int k = k0 + quad * 8;
        const bf16x8 bd = ldb32(dw, brow + k);
#pragma unroll
        for (int i = 0; i < 2; ++i) {
            const bf16x8 af = *(const bf16x8*)(A + (m0 + i * 16 + r16) * H4 + k);
            ac[i] = __builtin_amdgcn_mfma_f32_16x16x32_bf16(af, bd, ac[i], 0, 0, 0);
        }
    }
    const int ocol = n0 + r16;
    const float dbv = db[ocol];
#pragma unroll
    for (int i = 0; i < 2; ++i)
#pragma unroll
        for (int r = 0; r < 4; ++r) {
            const int orow = m0 + i * 16 + quad * 4 + r;
            dout[orow * H + ocol] = ac[i][r] + dbv + predf[orow * H + ocol];
        }
}

__global__ __launch_bounds__(256) void k_ln1(
    const float* __restrict__ dout,
    const float* __restrict__ nw,
    const float* __restrict__ nb,
    float* __restrict__ out)
{
    const int m = blockIdx.x;
    const int tid = threadIdx.x;
    const float* rowp = dout + m * H;

    float v[3];
    float s = 0.f, s2 = 0.f;
#pragma unroll
    for (int j = 0; j < 3; ++j) {
        v[j] = rowp[tid + 256 * j];
        s += v[j];
        s2 += v[j] * v[j];
    }
#pragma unroll
    for (int off = 32; off >= 1; off >>= 1) {
        s  += __shfl_xor(s, off, 64);
        s2 += __shfl_xor(s2, off, 64);
    }
    __shared__ float rs[4], rs2[4];
    const int wid = tid >> 6, lane = tid & 63;
    if (lane == 0) { rs[wid] = s; rs2[wid] = s2; }
    __syncthreads();
    s  = rs[0] + rs[1] + rs[2] + rs[3];
    s2 = rs2[0] + rs2[1] + rs2[2] + rs2[3];
    const float mu  = s / (float)H;
    const float var = s2 / (float)H - mu * mu;
    const float inv = rsqrtf(var + 1e-5f);
#pragma unroll
    for (int j = 0; j < 3; ++j) {
        const int hh = tid + 256 * j;
        out[m * H + hh] = (v[j] - mu) * inv * nw[hh] + nb[hh];
    }
}

// ---------------- launch ----------------
extern "C" void kernel_launch(void* const* d_in, const int* in_sizes, int n_in,
                              void* d_out, int out_size, void* d_ws, size_t ws_size,
                              hipStream_t stream)
{
    const float* x   = (const float*)d_in[0];
    const float* W0  = (const float*)d_in[1];
    const float* b0  = (const float*)d_in[2];
    const float* gw  = (const float*)d_in[3];
    const float* gb  = (const float*)d_in[4];
    const float* uw  = (const float*)d_in[5];
    const float* ub  = (const float*)d_in[6];
    const float* dw  = (const float*)d_in[7];
    const float* db  = (const float*)d_in[8];
    const float* nw  = (const float*)d_in[9];
    const float* nb  = (const float*)d_in[10];

    char* ws = (char*)d_ws;
    float*          pred_f = (float*)(ws);                       // 1,572,864
    __hip_bfloat16* pred_h = (__hip_bfloat16*)(ws + 1572864);    //   786,432
    __hip_bfloat16* hid    = (__hip_bfloat16*)(ws + 2359296);    // 3,145,728
    float*          base0  = (float*)(ws + 5505024);             // 1,572,864
    float*          dout_f = (float*)(ws + 5505024);             // alias (fallback only)
    float*          g      = (float*)(ws + 7077888);             //   524,288
    short*          Xhi    = (short*)(ws + 7602176);             //   786,432
    short*          Xlo    = (short*)(ws + 8388608);             //   786,432
    short*          Whi    = (short*)(ws + 9175040);             // 1,179,648
    short*          Wlo    = (short*)(ws + 10354688);            // 1,179,648
    float*          U      = (float*)(ws + 11534336);            //   131,072
    short* gw2 = (short*)(ws + 11665408);
    short* uw2 = (short*)(ws + 11665408 + 4718592);
    short* dw2 = (short*)(ws + 11665408 + 2 * 4718592);
    float* dpart = (float*)(ws + 25821184);                      // 4 x 1,572,864
    const size_t WNEED = 25821184ULL + 6291456ULL;
    const bool wb = ws_size >= WNEED;

    const int ngroups = wb ? 2015232 : 245760;
    k_stage<<<dim3(ngroups / 256), 256, 0, stream>>>(
        x, W0, gw, uw, dw, Xhi, Xlo, Whi, Wlo, gw2, uw2, dw2);
    k_gram_base<<<dim3(128), 256, 0, stream>>>(Xhi, Xlo, Whi, Wlo, b0, g, base0);
    k_inv<<<dim3(BB * NC), 256, 0, stream>>>(g, U);
    k_recur6<<<dim3(96), 256, 0, stream>>>(x, base0, g, U, pred_f, pred_h);
    if (wb) {
        k_gateup4<<<dim3(H4 / 64, M / 64), 256, 0, stream>>>(pred_h, gw2, gb, uw2, ub, hid);
        k_down4<<<dim3(H / 64, M / 32, 4), 256, 0, stream>>>(hid, dw2, dpart);
        k_ln2<<<dim3(M), 256, 0, stream>>>(dpart, db, pred_f, nw, nb, (float*)d_out);
    } else {
        k_gateup2<<<dim3(H4 / 64, M / 64), 256, 0, stream>>>(pred_h, gw, gb, uw, ub, hid);
        k_down2f<<<dim3(H / 64, M / 32), 256, 0, stream>>>(hid, dw, db, pred_f, dout_f);
        k_ln1<<<dim3(M), 256, 0, stream>>>(dout_f, nw, nb, (float*)d_out);
    }
}

// Round 9
// 186.651 us; speedup vs baseline: 1.2769x; 1.1027x over previous
//
#include <hip/hip_runtime.h>
#include <hip/hip_bf16.h>

#define H   768
#define H4  3072
#define S   256
#define BB  2
#define M   (BB * S)          // 512 rows of (b,t)
#define LRC 0.01f
#define C   64                // chunk size
#define NC  (S / C)           // 4 chunks

typedef __attribute__((ext_vector_type(8))) short bf16x8;
typedef __attribute__((ext_vector_type(4))) float f32x4;

__device__ inline short bfbits(float f) {
    __hip_bfloat16 h = __float2bfloat16(f);
    return *reinterpret_cast<short*>(&h);
}

// ---------------- K_stage: all input staging in ONE kernel ----------------
__global__ __launch_bounds__(256) void k_stage(
    const float* __restrict__ x,  const float* __restrict__ W0,
    const float* __restrict__ gw, const float* __restrict__ uw,
    const float* __restrict__ dw,
    short* __restrict__ Xhi, short* __restrict__ Xlo,
    short* __restrict__ Whi, short* __restrict__ Wlo,
    short* __restrict__ gw2, short* __restrict__ uw2, short* __restrict__ dw2)
{
    const long gid = (long)blockIdx.x * 256 + threadIdx.x;
    const float* src; short* hp; short* lp = nullptr; long base;
    if (gid < 98304)        { src = x;  hp = Xhi; lp = Xlo; base = 0; }
    else if (gid < 245760)  { src = W0; hp = Whi; lp = Wlo; base = 98304; }
    else if (gid < 835584)  { src = gw; hp = gw2; base = 245760; }
    else if (gid < 1425408) { src = uw; hp = uw2; base = 835584; }
    else                    { src = dw; hp = dw2; base = 1425408; }
    const long i = (gid - base) * 4;
    const float4 v = *(const float4*)(src + i);
    const float vf[4] = {v.x, v.y, v.z, v.w};
    short h4[4], l4[4];
#pragma unroll
    for (int j = 0; j < 4; ++j) {
        h4[j] = bfbits(vf[j]);
        __hip_bfloat16 hb = *reinterpret_cast<__hip_bfloat16*>(&h4[j]);
        l4[j] = bfbits(vf[j] - __bfloat162float(hb));
    }
    *(uint2*)(hp + i) = *(uint2*)h4;
    if (lp) *(uint2*)(lp + i) = *(uint2*)l4;
}

// ---------------- K_gram_base2: merged Gram + Base0 GEMMs, 256 wgs --------
// blocks [0,64): G = X.X^T + 1 (32m x 64n tiles); [64,256): Base0 = X.W0^T + b0
__global__ __launch_bounds__(256) void k_gram_base2(
    const short* __restrict__ Xhi, const short* __restrict__ Xlo,
    const short* __restrict__ Whi, const short* __restrict__ Wlo,
    const float* __restrict__ b0,
    float* __restrict__ g, float* __restrict__ base0)
{
    const int wid = threadIdx.x >> 6, lane = threadIdx.x & 63;
    const int r16 = lane & 15, quad = lane >> 4;
    const int id = blockIdx.x;

    f32x4 acc[2];
    acc[0] = (f32x4){0, 0, 0, 0};
    acc[1] = (f32x4){0, 0, 0, 0};

    if (id < 64) {  // ---- gram ----
        const int bx = id & 3, by = (id >> 2) & 7, b = id >> 5;
        const int m0 = by * 32, n0 = bx * 64 + wid * 16;
        const short* XH = Xhi + b * S * H;
        const short* XL = Xlo + b * S * H;
        for (int k0 = 0; k0 < H; k0 += 32) {
            const int k = k0 + quad * 8;
            const bf16x8 bh = *(const bf16x8*)(XH + (n0 + r16) * H + k);
            const bf16x8 bl = *(const bf16x8*)(XL + (n0 + r16) * H + k);
#pragma unroll
            for (int i = 0; i < 2; ++i) {
                const bf16x8 ah = *(const bf16x8*)(XH + (m0 + i * 16 + r16) * H + k);
                const bf16x8 al = *(const bf16x8*)(XL + (m0 + i * 16 + r16) * H + k);
                acc[i] = __builtin_amdgcn_mfma_f32_16x16x32_bf16(ah, bh, acc[i], 0, 0, 0);
                acc[i] = __builtin_amdgcn_mfma_f32_16x16x32_bf16(ah, bl, acc[i], 0, 0, 0);
                acc[i] = __builtin_amdgcn_mfma_f32_16x16x32_bf16(al, bh, acc[i], 0, 0, 0);
            }
        }
        const int col = n0 + r16;
#pragma unroll
        for (int i = 0; i < 2; ++i)
#pragma unroll
            for (int r = 0; r < 4; ++r) {
                const int row = m0 + i * 16 + quad * 4 + r;
                g[(b * S + row) * S + col] = acc[i][r] + 1.f;
            }
    } else {        // ---- base ----
        const int id2 = id - 64;
        const int m0 = (id2 / 12) * 32, n0 = (id2 % 12) * 64 + wid * 16;
        for (int k0 = 0; k0 < H; k0 += 32) {
            const int k = k0 + quad * 8;
            const bf16x8 bh = *(const bf16x8*)(Whi + (n0 + r16) * H + k);
            const bf16x8 bl = *(const bf16x8*)(Wlo + (n0 + r16) * H + k);
#pragma unroll
            for (int i = 0; i < 2; ++i) {
                const bf16x8 ah = *(const bf16x8*)(Xhi + (m0 + i * 16 + r16) * H + k);
                const bf16x8 al = *(const bf16x8*)(Xlo + (m0 + i * 16 + r16) * H + k);
                acc[i] = __builtin_amdgcn_mfma_f32_16x16x32_bf16(ah, bh, acc[i], 0, 0, 0);
                acc[i] = __builtin_amdgcn_mfma_f32_16x16x32_bf16(ah, bl, acc[i], 0, 0, 0);
                acc[i] = __builtin_amdgcn_mfma_f32_16x16x32_bf16(al, bh, acc[i], 0, 0, 0);
            }
        }
        const int col = n0 + r16;
        const float bv = b0[col];
#pragma unroll
        for (int i = 0; i < 2; ++i)
#pragma unroll
            for (int r = 0; r < 4; ++r) {
                const int row = m0 + i * 16 + quad * 4 + r;
                base0[row * H + col] = acc[i][r] + bv;
            }
    }
}

// ---------------- K_inv: U_c = T_c^{-1} for each (b, chunk) ---------------
__global__ __launch_bounds__(256) void k_inv(
    const float* __restrict__ g, float* __restrict__ U)
{
    __shared__ float Gi[C * 65];
    const int tid = threadIdx.x;
    const int w = tid >> 6, lane = tid & 63;
    const int b = blockIdx.x >> 2, c = blockIdx.x & 3;
    const int t0 = c * C;

#pragma unroll
    for (int j = 0; j < 16; ++j) {
        const int idx = tid + 256 * j;
        const int row = idx >> 6, col = idx & 63;
        Gi[row * 65 + col] = g[(long)(b * S + t0 + row) * S + t0 + col];
    }
    __syncthreads();

    const int j0 = w * 16;
    float R[16];
#pragma unroll
    for (int i = 0; i < 16; ++i) R[i] = (lane == j0 + i) ? 1.f : 0.f;

    for (int s = 0; s < C - 1; ++s) {
        const float Gv = Gi[s * 65 + lane];
        const float mlt = (lane > s) ? LRC : 0.f;
#pragma unroll
        for (int i = 0; i < 16; ++i) {
            const float dsb = __shfl(R[i], s, 64);
            R[i] -= mlt * Gv * dsb;
        }
    }
    float* Ub = U + (long)(b * NC + c) * C * C;
#pragma unroll
    for (int i = 0; i < 16; ++i)
        Ub[lane * C + j0 + i] = R[i];
}

// ---------------- K_recur7: solve via U; 8 h per wg, 192 wgs --------------
__global__ __launch_bounds__(256) void k_recur7(
    const float* __restrict__ x,
    const float* __restrict__ base0,
    const float* __restrict__ g,
    const float* __restrict__ U,
    float* __restrict__ pred_f,
    __hip_bfloat16* __restrict__ pred_h)
{
    __shared__ float  tB[64 * 9];
    __shared__ float  tX[64 * 9];
    __shared__ float2 Dl2[256 * 4];      // D history: row t, slot wave (8 KB)
    __shared__ float2 Rl2[4 * 64];       // per-wave R vector (2 KB)
    __shared__ float  Us[64 * 65];
    __shared__ float  Gslab[192 * 64];   // cross-chunk G rows (48 KB max)
    const int tid = threadIdx.x;
    const int w = tid >> 6, lane = tid & 63;
    const int b = blockIdx.x / 96, hb = blockIdx.x % 96;
    const int h0 = hb * 8;
    const int ho = w * 2;                // 2 h per wave
    const int ct = tid >> 2;             // staging row 0..63
    const int cq = (tid & 3) * 2;        // staging col {0,2,4,6}

    for (int c = 0; c < NC; ++c) {
        const int t0 = c * C;
        __syncthreads();
        {   // stage tB = Base0 - Xn, tX = Xn, Us = U_c, Gslab = G[0:t0][t0+.]
            const int gm = b * S + t0 + ct;
            const float2 bv = *(const float2*)(base0 + gm * H + h0 + cq);
            float2 xv = {0.f, 0.f};
            if (t0 + ct + 1 < S)
                xv = *(const float2*)(x + (gm + 1) * H + h0 + cq);
            tB[ct * 9 + cq + 0] = bv.x - xv.x;
            tB[ct * 9 + cq + 1] = bv.y - xv.y;
            tX[ct * 9 + cq + 0] = xv.x;
            tX[ct * 9 + cq + 1] = xv.y;
            const float* Ub = U + (long)(b * NC + c) * C * C;
#pragma unroll
            for (int j = 0; j < 16; ++j) {
                const int idx = tid + 256 * j;
                const int row = idx >> 6, col = idx & 63;
                Us[row * 65 + col] = Ub[row * C + col];
            }
            const float* gb = g + (long)(b * S) * S + t0;
            for (int i = tid; i < t0 * 64; i += 256) {
                const int row = i >> 6, col = i & 63;
                Gslab[i] = gb[(long)row * S + col];
            }
        }
        __syncthreads();
        float R[2], Xn[2];
#pragma unroll
        for (int h = 0; h < 2; ++h) {
            R[h]  = tB[lane * 9 + ho + h];
            Xn[h] = tX[lane * 9 + ho + h];
        }
        // cross-chunk corrections (Dl2 slot w written by THIS wave earlier)
#pragma unroll 8
        for (int cs = 0; cs < t0; ++cs) {
            const float Gv = Gslab[cs * 64 + lane];
            const float2 dr = Dl2[cs * 4 + w];    // broadcast read
            R[0] -= LRC * Gv * dr.x;
            R[1] -= LRC * Gv * dr.y;
        }
        // publish R for this wave, then D[t] = sum_s U[t][s] * R[s]
        Rl2[w * 64 + lane] = (float2){R[0], R[1]};
        float D[2] = {0.f, 0.f};
#pragma unroll 8
        for (int s = 0; s < C; ++s) {
            const float2 rb = Rl2[w * 64 + s];    // broadcast read
            const float uv = Us[lane * 65 + s];   // U[t=lane][s]
            D[0] += uv * rb.x;
            D[1] += uv * rb.y;
        }
        Dl2[(t0 + lane) * 4 + w] = (float2){D[0], D[1]};
        __syncthreads();
#pragma unroll
        for (int h = 0; h < 2; ++h) tB[lane * 9 + ho + h] = D[h] + Xn[h];
        __syncthreads();
        {
            const int gm = b * S + t0 + ct;
            float2 pv;
            pv.x = tB[ct * 9 + cq + 0];
            pv.y = tB[ct * 9 + cq + 1];
            *(float2*)(pred_f + gm * H + h0 + cq) = pv;
            short p2[2];
            p2[0] = bfbits(pv.x); p2[1] = bfbits(pv.y);
            *(unsigned int*)((short*)pred_h + gm * H + h0 + cq) = *(unsigned int*)p2;
        }
    }
}

// ---------------- K_gateup4: LDS-tiled fused gate+up GEMM, 64x64 tiles ---
#define RS 40
__global__ __launch_bounds__(256) void k_gateup4(
    const __hip_bfloat16* __restrict__ predh,
    const short* __restrict__ gwp, const float* __restrict__ gb,
    const short* __restrict__ uwp, const float* __restrict__ ub,
    __hip_bfloat16* __restrict__ hid)
{
    __shared__ int4 smv[960];            // 15360 B
    short* sm = (short*)smv;
    short* sA = sm;                      // 64 x RS
    short* sG = sm + 64 * RS;            // 64 x RS
    short* sU = sm + 128 * RS;           // 64 x RS

    const int tid = threadIdx.x;
    const int wid = tid >> 6, lane = tid & 63;
    const int r16 = lane & 15, quad = lane >> 4;
    const int wm = wid & 1, wn = (wid >> 1) & 1;
    const int n0 = blockIdx.x * 64;
    const int m0 = blockIdx.y * 64;

    const int srow = tid >> 2;
    const int sch  = (tid & 3) * 8;
    const short* A = (const short*)predh;

    f32x4 ag[2][2], au[2][2];
#pragma unroll
    for (int i = 0; i < 2; ++i)
#pragma unroll
        for (int j = 0; j < 2; ++j) { ag[i][j] = (f32x4){0,0,0,0}; au[i][j] = (f32x4){0,0,0,0}; }

    int4 rA, rG, rU;
    rA = *(const int4*)(A   + (m0 + srow) * H + sch);
    rG = *(const int4*)(gwp + (n0 + srow) * H + sch);
    rU = *(const int4*)(uwp + (n0 + srow) * H + sch);
    for (int it = 0; it < 24; ++it) {
        *(int4*)(sA + srow * RS + sch) = rA;
        *(int4*)(sG + srow * RS + sch) = rG;
        *(int4*)(sU + srow * RS + sch) = rU;
        __syncthreads();
        if (it < 23) {
            const int k = (it + 1) * 32 + sch;
            rA = *(const int4*)(A   + (m0 + srow) * H + k);
            rG = *(const int4*)(gwp + (n0 + srow) * H + k);
            rU = *(const int4*)(uwp + (n0 + srow) * H + k);
        }
        bf16x8 aF[2], gF[2], uF[2];
#pragma unroll
        for (int i = 0; i < 2; ++i) {
            aF[i] = *(const bf16x8*)(sA + (wm * 32 + i * 16 + r16) * RS + quad * 8);
            gF[i] = *(const bf16x8*)(sG + (wn * 32 + i * 16 + r16) * RS + quad * 8);
            uF[i] = *(const bf16x8*)(sU + (wn * 32 + i * 16 + r16) * RS + quad * 8);
        }
#pragma unroll
        for (int i = 0; i < 2; ++i)
#pragma unroll
            for (int j = 0; j < 2; ++j) {
                ag[i][j] = __builtin_amdgcn_mfma_f32_16x16x32_bf16(aF[i], gF[j], ag[i][j], 0, 0, 0);
                au[i][j] = __builtin_amdgcn_mfma_f32_16x16x32_bf16(aF[i], uF[j], au[i][j], 0, 0, 0);
            }
        __syncthreads();
    }
#pragma unroll
    for (int j = 0; j < 2; ++j) {
        const int ocol = n0 + wn * 32 + j * 16 + r16;
        const float gbv = gb[ocol], ubv = ub[ocol];
#pragma unroll
        for (int i = 0; i < 2; ++i)
#pragma unroll
            for (int r = 0; r < 4; ++r) {
                const int orow = m0 + wm * 32 + i * 16 + quad * 4 + r;
                const float gg = ag[i][j][r] + gbv;
                const float u  = au[i][j][r] + ubv;
                const float sg = 1.f / (1.f + __expf(-gg));
                hid[orow * H4 + ocol] = __float2bfloat16(sg * u);
            }
    }
}

// ---------------- K_down4: split-K down GEMM -> f32 partials -------------
__device__ inline bf16x8 ldb16(const void* p, long off) {
    return *(const bf16x8*)((const short*)p + off);
}
__global__ __launch_bounds__(256) void k_down4(
    const __hip_bfloat16* __restrict__ hid,
    const short* __restrict__ dwp,
    float* __restrict__ dpart)
{
    const int wid = threadIdx.x >> 6, lane = threadIdx.x & 63;
    const int r16 = lane & 15, quad = lane >> 4;
    const int m0 = blockIdx.y * 32;
    const int n0 = blockIdx.x * 64 + wid * 16;
    const int kz = blockIdx.z;

    f32x4 ac[2];
    ac[0] = (f32x4){0,0,0,0}; ac[1] = (f32x4){0,0,0,0};
    const short* A = (const short*)hid;
    const long brow = (long)(n0 + r16) * H4;

    const int kbeg = kz * 768, kend = kbeg + 768;
    for (int k0 = kbeg; k0 < kend; k0 += 32) {
        const int k = k0 + quad * 8;
        const bf16x8 bd = ldb16(dwp, brow + k);
#pragma unroll
        for (int i = 0; i < 2; ++i) {
            const bf16x8 af = *(const bf16x8*)(A + (m0 + i * 16 + r16) * H4 + k);
            ac[i] = __builtin_amdgcn_mfma_f32_16x16x32_bf16(af, bd, ac[i], 0, 0, 0);
        }
    }
    float* dp = dpart + (long)kz * M * H;
    const int ocol = n0 + r16;
#pragma unroll
    for (int i = 0; i < 2; ++i)
#pragma unroll
        for (int r = 0; r < 4; ++r) {
            const int orow = m0 + i * 16 + quad * 4 + r;
            dp[orow * H + ocol] = ac[i][r];
        }
}

// ---------------- K_ln2: sum partials + bias + residual + LayerNorm ------
__global__ __launch_bounds__(256) void k_ln2(
    const float* __restrict__ dpart,
    const float* __restrict__ db,
    const float* __restrict__ predf,
    const float* __restrict__ nw,
    const float* __restrict__ nb,
    float* __restrict__ out)
{
    const int m = blockIdx.x;
    const int tid = threadIdx.x;

    float v[3];
    float s = 0.f, s2 = 0.f;
#pragma unroll
    for (int j = 0; j < 3; ++j) {
        const int hh = tid + 256 * j;
        const long o = (long)m * H + hh;
        float t = dpart[o] + dpart[o + (long)M * H]
                + dpart[o + 2L * M * H] + dpart[o + 3L * M * H]
                + db[hh] + predf[o];
        v[j] = t;
        s += t;
        s2 += t * t;
    }
#pragma unroll
    for (int off = 32; off >= 1; off >>= 1) {
        s  += __shfl_xor(s, off, 64);
        s2 += __shfl_xor(s2, off, 64);
    }
    __shared__ float rs[4], rs2[4];
    const int wid = tid >> 6, lane = tid & 63;
    if (lane == 0) { rs[wid] = s; rs2[wid] = s2; }
    __syncthreads();
    s  = rs[0] + rs[1] + rs[2] + rs[3];
    s2 = rs2[0] + rs2[1] + rs2[2] + rs2[3];
    const float mu  = s / (float)H;
    const float var = s2 / (float)H - mu * mu;
    const float inv = rsqrtf(var + 1e-5f);
#pragma unroll
    for (int j = 0; j < 3; ++j) {
        const int hh = tid + 256 * j;
        out[m * H + hh] = (v[j] - mu) * inv * nw[hh] + nb[hh];
    }
}

// ---------------- fallbacks (ws too small): direct-global f32 GEMMs ------
__device__ inline bf16x8 ldb32(const void* p, long off) {
    const float* f = (const float*)p + off;
    const float4 a = *(const float4*)f;
    const float4 b = *(const float4*)(f + 4);
    bf16x8 r;
    r[0] = bfbits(a.x); r[1] = bfbits(a.y); r[2] = bfbits(a.z); r[3] = bfbits(a.w);
    r[4] = bfbits(b.x); r[5] = bfbits(b.y); r[6] = bfbits(b.z); r[7] = bfbits(b.w);
    return r;
}

__global__ __launch_bounds__(256) void k_gateup2(
    const __hip_bfloat16* __restrict__ predh,
    const void* __restrict__ gw, const float* __restrict__ gb,
    const void* __restrict__ uw, const float* __restrict__ ub,
    __hip_bfloat16* __restrict__ hid)
{
    const int wid = threadIdx.x >> 6, lane = threadIdx.x & 63;
    const int r16 = lane & 15, quad = lane >> 4;
    const int m0 = blockIdx.y * 64;
    const int n0 = blockIdx.x * 64 + wid * 16;

    f32x4 ag[4], au[4];
#pragma unroll
    for (int i = 0; i < 4; ++i) { ag[i] = (f32x4){0,0,0,0}; au[i] = (f32x4){0,0,0,0}; }
    const short* A = (const short*)predh;
    const long brow = (long)(n0 + r16) * H;

    for (int k0 = 0; k0 < H; k0 += 32) {
        const int k = k0 + quad * 8;
        const bf16x8 bg = ldb32(gw, brow + k);
        const bf16x8 bu = ldb32(uw, brow + k);
#pragma unroll
        for (int i = 0; i < 4; ++i) {
            const bf16x8 af = *(const bf16x8*)(A + (m0 + i * 16 + r16) * H + k);
            ag[i] = __builtin_amdgcn_mfma_f32_16x16x32_bf16(af, bg, ag[i], 0, 0, 0);
            au[i] = __builtin_amdgcn_mfma_f32_16x16x32_bf16(af, bu, au[i], 0, 0, 0);
        }
    }
    const int ocol = n0 + r16;
    const float gbv = gb[ocol], ubv = ub[ocol];
#pragma unroll
    for (int i = 0; i < 4; ++i)
#pragma unroll
        for (int r = 0; r < 4; ++r) {
            const int orow = m0 + i * 16 + quad * 4 + r;
            const float gg = ag[i][r] + gbv;
            const float u = au[i][r] + ubv;
            const float sg = 1.f / (1.f + __expf(-gg));
            hid[orow * H4 + ocol] = __float2bfloat16(sg * u);
        }
}

__global__ __launch_bounds__(256) void k_down2f(
    const __hip_bfloat16* __restrict__ hid,
    const void* __restrict__ dw, const float* __restrict__ db,
    const float* __restrict__ predf, float* __restrict__ dout)
{
    const int wid = threadIdx.x >> 6, lane = threadIdx.x & 63;
    const int r16 = lane & 15, quad = lane >> 4;
    const int m0 = blockIdx.y * 32;
    const int n0 = blockIdx.x * 64 + wid * 16;

    f32x4 ac[2];
    ac[0] = (f32x4){0,0,0,0}; ac[1] = (f32x4){0,0,0,0};
    const short* A = (const short*)hid;
    const long brow = (long)(n0 + r16) * H4;

    for (int k0 = 0; k0 < H4; k0 += 32) {
        const int k = k0 + quad * 8;
        const bf16x8 bd = ldb32(dw, brow + k);
#pragma unroll
        for (int i = 0; i < 2; ++i) {
            const bf16x8 af = *(const bf16x8*)(A + (m0 + i * 16 + r16) * H4 + k);
            ac[i] = __builtin_amdgcn_mfma_f32_16x16x32_bf16(af, bd, ac[i], 0, 0, 0);
        }
    }
    const int ocol = n0 + r16;
    const float dbv = db[ocol];
#pragma unroll
    for (int i = 0; i < 2; ++i)
#pragma unroll
        for (int r = 0; r < 4; ++r) {
            const int orow = m0 + i * 16 + quad * 4 + r;
            dout[orow * H + ocol] = ac[i][r] + dbv + predf[orow * H + ocol];
        }
}

__global__ __launch_bounds__(256) void k_ln1(
    const float* __restrict__ dout,
    const float* __restrict__ nw,
    const float* __restrict__ nb,
    float* __restrict__ out)
{
    const int m = blockIdx.x;
    const int tid = threadIdx.x;
    const float* rowp = dout + m * H;

    float v[3];
    float s = 0.f, s2 = 0.f;
#pragma unroll
    for (int j = 0; j < 3; ++j) {
        v[j] = rowp[tid + 256 * j];
        s += v[j];
        s2 += v[j] * v[j];
    }
#pragma unroll
    for (int off = 32; off >= 1; off >>= 1) {
        s  += __shfl_xor(s, off, 64);
        s2 += __shfl_xor(s2, off, 64);
    }
    __shared__ float rs[4], rs2[4];
    const int wid = tid >> 6, lane = tid & 63;
    if (lane == 0) { rs[wid] = s; rs2[wid] = s2; }
    __syncthreads();
    s  = rs[0] + rs[1] + rs[2] + rs[3];
    s2 = rs2[0] + rs2[1] + rs2[2] + rs2[3];
    const float mu  = s / (float)H;
    const float var = s2 / (float)H - mu * mu;
    const float inv = rsqrtf(var + 1e-5f);
#pragma unroll
    for (int j = 0; j < 3; ++j) {
        const int hh = tid + 256 * j;
        out[m * H + hh] = (v[j] - mu) * inv * nw[hh] + nb[hh];
    }
}

// ---------------- launch ----------------
extern "C" void kernel_launch(void* const* d_in, const int* in_sizes, int n_in,
                              void* d_out, int out_size, void* d_ws, size_t ws_size,
                              hipStream_t stream)
{
    const float* x   = (const float*)d_in[0];
    const float* W0  = (const float*)d_in[1];
    const float* b0  = (const float*)d_in[2];
    const float* gw  = (const float*)d_in[3];
    const float* gb  = (const float*)d_in[4];
    const float* uw  = (const float*)d_in[5];
    const float* ub  = (const float*)d_in[6];
    const float* dw  = (const float*)d_in[7];
    const float* db  = (const float*)d_in[8];
    const float* nw  = (const float*)d_in[9];
    const float* nb  = (const float*)d_in[10];

    char* ws = (char*)d_ws;
    float*          pred_f = (float*)(ws);                       // 1,572,864
    __hip_bfloat16* pred_h = (__hip_bfloat16*)(ws + 1572864);    //   786,432
    __hip_bfloat16* hid    = (__hip_bfloat16*)(ws + 2359296);    // 3,145,728
    float*          base0  = (float*)(ws + 5505024);             // 1,572,864
    float*          dout_f = (float*)(ws + 5505024);             // alias (fallback only)
    float*          g      = (float*)(ws + 7077888);             //   524,288
    short*          Xhi    = (short*)(ws + 7602176);             //   786,432
    short*          Xlo    = (short*)(ws + 8388608);             //   786,432
    short*          Whi    = (short*)(ws + 9175040);             // 1,179,648
    short*          Wlo    = (short*)(ws + 10354688);            // 1,179,648
    float*          U      = (float*)(ws + 11534336);            //   131,072
    short* gw2 = (short*)(ws + 11665408);
    short* uw2 = (short*)(ws + 11665408 + 4718592);
    short* dw2 = (short*)(ws + 11665408 + 2 * 4718592);
    float* dpart = (float*)(ws + 25821184);                      // 4 x 1,572,864
    const size_t WNEED = 25821184ULL + 6291456ULL;
    const bool wb = ws_size >= WNEED;

    const int ngroups = wb ? 2015232 : 245760;
    k_stage<<<dim3(ngroups / 256), 256, 0, stream>>>(
        x, W0, gw, uw, dw, Xhi, Xlo, Whi, Wlo, gw2, uw2, dw2);
    k_gram_base2<<<dim3(256), 256, 0, stream>>>(Xhi, Xlo, Whi, Wlo, b0, g, base0);
    k_inv<<<dim3(BB * NC), 256, 0, stream>>>(g, U);
    k_recur7<<<dim3(192), 256, 0, stream>>>(x, base0, g, U, pred_f, pred_h);
    if (wb) {
        k_gateup4<<<dim3(H4 / 64, M / 64), 256, 0, stream>>>(pred_h, gw2, gb, uw2, ub, hid);
        k_down4<<<dim3(H / 64, M / 32, 4), 256, 0, stream>>>(hid, dw2, dpart);
        k_ln2<<<dim3(M), 256, 0, stream>>>(dpart, db, pred_f, nw, nb, (float*)d_out);
    } else {
        k_gateup2<<<dim3(H4 / 64, M / 64), 256, 0, stream>>>(pred_h, gw, gb, uw, ub, hid);
        k_down2f<<<dim3(H / 64, M / 32), 256, 0, stream>>>(hid, dw, db, pred_f, dout_f);
        k_ln1<<<dim3(M), 256, 0, stream>>>(dout_f, nw, nb, (float*)d_out);
    }
}